// Round 2
// baseline (2427.244 us; speedup 1.0000x reference)
//
#include <hip/hip_runtime.h>
#include <math.h>

#define NN 16384
#define CD 512
#define EE 262144
#define LL 2048

typedef __attribute__((ext_vector_type(8))) short short8;
typedef __attribute__((ext_vector_type(4))) float floatx4;

__device__ __forceinline__ unsigned short f2b(float f){
  unsigned int u = __float_as_uint(f);
  unsigned int r = (u + 0x7fffu + ((u>>16)&1u)) >> 16;
  return (unsigned short)r;
}
__device__ __forceinline__ float b2f(unsigned short h){
  return __uint_as_float(((unsigned int)h)<<16);
}

// ---------------- prep kernels ----------------

// W: K x Nsub (row pitch `pitch`, col offset col0) -> Bt: Npad x K bf16 (zero-padded rows)
__global__ void transposeW(const float* __restrict__ W, short* __restrict__ Bt,
                           int K, int Nsub, int Npad, int pitch, int col0){
  int idx = blockIdx.x*256 + threadIdx.x;
  if (idx >= Npad*K) return;
  int n = idx / K, k = idx - n*K;
  float v = (n < Nsub) ? W[(size_t)k*pitch + col0 + n] : 0.f;
  Bt[idx] = (short)f2b(v);
}

// Wfused^T[j][i] = sum_r W_xp[i,r]*W_dt[r,j]  (512x512 bf16, Bt layout)
__global__ void fuse_wdt(const float* __restrict__ W_xp, const float* __restrict__ W_dt,
                         short* __restrict__ Wft){
  int idx = blockIdx.x*256 + threadIdx.x;   // 512*512
  if (idx >= 512*512) return;
  int i = idx & 511;      // input channel (k-dim)
  int j = idx >> 9;       // output channel
  float a = 0.f;
  #pragma unroll 8
  for (int r = 0; r < 32; ++r) a += W_xp[(size_t)i*64 + r] * W_dt[(size_t)r*512 + j];
  Wft[idx] = (short)f2b(a);
}

__global__ void pad_bias(const float* __restrict__ b, float* __restrict__ out){
  int i = blockIdx.x*256 + threadIdx.x;
  if (i < 512) out[i] = (i < 496) ? b[i] : 0.f;
}

// x (16384 x 1026) cols 2..1025 -> Xb bf16 (16384 x 1024)
__global__ void conv_x(const float* __restrict__ x, short* __restrict__ Xb){
  int idx = blockIdx.x*256 + threadIdx.x;
  if (idx >= NN*1024) return;
  int r = idx >> 10, c = idx & 1023;
  Xb[idx] = (short)f2b(x[(size_t)r*1026 + 2 + c]);
}

// positional encodings into h0b cols 496..511
__global__ void pe_fill(const float* __restrict__ x, unsigned short* __restrict__ h0b){
  int r = blockIdx.x*256 + threadIdx.x;
  if (r >= NN) return;
  float p0 = x[(size_t)r*1026 + 0], p1 = x[(size_t)r*1026 + 1];
  const float dn[4] = {1.f, 10.f, 100.f, 1000.f};
  unsigned short* o = h0b + (size_t)r*512 + 496;
  #pragma unroll
  for (int q = 0; q < 4; ++q){
    o[2*q]     = f2b(sinf(p0/dn[q]));
    o[2*q+1]   = f2b(cosf(p0/dn[q]));
    o[8+2*q]   = f2b(sinf(p1/dn[q]));
    o[8+2*q+1] = f2b(cosf(p1/dn[q]));
  }
}

// ---------------- GEMM (A MxK bf16 row-major, Bt NpadxK bf16 row-major) ----------------
// 128x128 tile, 4 waves (2x2), each wave 64x64 via 4x4 mfma_f32_16x16x32_bf16 frags.
__global__ __launch_bounds__(256)
void gemm_bt(const short* __restrict__ A, const short* __restrict__ Bt,
             float* __restrict__ Cf, unsigned short* __restrict__ Cb,
             const float* __restrict__ bias, const float* __restrict__ resid,
             int K, int Nvalid, int epi){
  __shared__ __align__(16) short As[128*32];
  __shared__ __align__(16) short Bs[128*32];
  int tid = threadIdx.x;
  int m0 = blockIdx.x * 128;
  int n0 = blockIdx.y * 128;
  int lane = tid & 63, wave = tid >> 6;
  int wm = wave >> 1, wn = wave & 1;
  int lr = lane & 15, lk = lane >> 4;

  floatx4 acc[4][4];
  #pragma unroll
  for (int m = 0; m < 4; ++m)
    #pragma unroll
    for (int n = 0; n < 4; ++n) acc[m][n] = (floatx4)0.f;

  int r0 = tid >> 1;
  int c0 = (tid & 1) * 16;

  for (int k0 = 0; k0 < K; k0 += 32){
    __syncthreads();
    const short8* pa = (const short8*)(A  + (size_t)(m0 + r0)*K + k0 + c0);
    const short8* pb = (const short8*)(Bt + (size_t)(n0 + r0)*K + k0 + c0);
    *(short8*)&As[r0*32 + c0]     = pa[0];
    *(short8*)&As[r0*32 + c0 + 8] = pa[1];
    *(short8*)&Bs[r0*32 + c0]     = pb[0];
    *(short8*)&Bs[r0*32 + c0 + 8] = pb[1];
    __syncthreads();
    short8 af[4], bf[4];
    #pragma unroll
    for (int m = 0; m < 4; ++m) af[m] = *(const short8*)&As[(wm*64 + m*16 + lr)*32 + lk*8];
    #pragma unroll
    for (int n = 0; n < 4; ++n) bf[n] = *(const short8*)&Bs[(wn*64 + n*16 + lr)*32 + lk*8];
    #pragma unroll
    for (int m = 0; m < 4; ++m)
      #pragma unroll
      for (int n = 0; n < 4; ++n)
        acc[m][n] = __builtin_amdgcn_mfma_f32_16x16x32_bf16(af[m], bf[n], acc[m][n], 0, 0, 0);
  }

  #pragma unroll
  for (int m = 0; m < 4; ++m){
    #pragma unroll
    for (int n = 0; n < 4; ++n){
      int col = n0 + wn*64 + n*16 + lr;
      if (col < Nvalid){
        #pragma unroll
        for (int r = 0; r < 4; ++r){
          int row = m0 + wm*64 + m*16 + lk*4 + r;
          float v = acc[m][n][r];
          if (bias)  v += bias[col];
          if (resid) v += resid[(size_t)row*Nvalid + col];
          if (epi == 1) v = fmaxf(v, 0.f);
          else if (epi == 2) v = (v > 20.f) ? v : log1pf(expf(v));
          size_t o = (size_t)row*Nvalid + col;
          if (Cf) Cf[o] = v;
          if (Cb) Cb[o] = f2b(v);
        }
      }
    }
  }
}

// ---------------- attention scalars ----------------
__global__ void att_proj(const unsigned short* __restrict__ xh,
                         const float* __restrict__ att_src, const float* __restrict__ att_dst,
                         float* __restrict__ a_s, float* __restrict__ a_d){
  int wave = threadIdx.x >> 6, lane = threadIdx.x & 63;
  int r = blockIdx.x*4 + wave;
  const unsigned short* xr = xh + (size_t)r*512;
  float ps = 0.f, pd = 0.f;
  #pragma unroll
  for (int j = 0; j < 8; ++j){
    float v = b2f(xr[lane + 64*j]);
    ps += v * att_src[lane + 64*j];
    pd += v * att_dst[lane + 64*j];
  }
  #pragma unroll
  for (int m = 32; m >= 1; m >>= 1){ ps += __shfl_xor(ps, m); pd += __shfl_xor(pd, m); }
  if (lane == 0){ a_s[r] = ps; a_d[r] = pd; }
}

// ---------------- GAT bucketing ----------------
__global__ void gat_hist(const int* __restrict__ ei, int* __restrict__ cnt){
  int e = blockIdx.x*256 + threadIdx.x;
  if (e < EE) atomicAdd(&cnt[ei[EE + e]], 1);
}

__global__ void gat_prefix(const int* __restrict__ cnt, int* __restrict__ offsets, int* __restrict__ cursor){
  __shared__ int part[256];
  int t = threadIdx.x;
  int s = 0;
  for (int i = 0; i < 64; ++i) s += cnt[t*64 + i];
  part[t] = s;
  __syncthreads();
  for (int off = 1; off < 256; off <<= 1){
    int v = (t >= off) ? part[t - off] : 0;
    __syncthreads();
    part[t] += v;
    __syncthreads();
  }
  int run = part[t] - s;   // exclusive base
  for (int i = 0; i < 64; ++i){
    int c = cnt[t*64 + i];
    offsets[t*64 + i] = run;
    cursor[t*64 + i]  = run;
    run += c;
  }
  if (t == 255) offsets[NN] = run;
}

__global__ void gat_scatter(const int* __restrict__ ei, const float* __restrict__ a_s,
                            const float* __restrict__ a_d, int* __restrict__ cursor,
                            int* __restrict__ srcs, float* __restrict__ alphas){
  int e = blockIdx.x*256 + threadIdx.x;
  if (e >= EE) return;
  int sN = ei[e], dN = ei[EE + e];
  int p = atomicAdd(&cursor[dN], 1);
  srcs[p] = sN;
  float al = a_s[sN] + a_d[dN];
  alphas[p] = (al > 0.f) ? al : 0.2f*al;
}

// one wave per dst node: softmax over in-edges (+self loop), gather-weighted sum
__global__ __launch_bounds__(256)
void gat_agg(const int* __restrict__ offsets, const int* __restrict__ srcs,
             const float* __restrict__ alphas, const unsigned short* __restrict__ xh,
             const float* __restrict__ a_s, const float* __restrict__ a_d,
             const float* __restrict__ b_gat, float* __restrict__ gat){
  int wave = threadIdx.x >> 6, lane = threadIdx.x & 63;
  int i = blockIdx.x*4 + wave;
  int beg = offsets[i], end = offsets[i+1];
  float asd = a_s[i] + a_d[i];
  float al0 = (asd > 0.f) ? asd : 0.2f*asd;
  float mx = al0;
  for (int p = beg + lane; p < end; p += 64) mx = fmaxf(mx, alphas[p]);
  #pragma unroll
  for (int m = 32; m >= 1; m >>= 1) mx = fmaxf(mx, __shfl_xor(mx, m));
  float se = 0.f;
  for (int p = beg + lane; p < end; p += 64) se += expf(alphas[p] - mx);
  #pragma unroll
  for (int m = 32; m >= 1; m >>= 1) se += __shfl_xor(se, m);
  float den = se + expf(al0 - mx);
  float inv = 1.f/(den + 1e-16f);
  float acc[8] = {0,0,0,0,0,0,0,0};
  for (int p = beg; p < end; ++p){
    float w = expf(alphas[p] - mx) * inv;
    const unsigned short* xr = xh + (size_t)srcs[p]*512;
    #pragma unroll
    for (int j = 0; j < 8; ++j) acc[j] += w * b2f(xr[lane + 64*j]);
  }
  {
    float w0 = expf(al0 - mx) * inv;
    const unsigned short* xr = xh + (size_t)i*512;
    #pragma unroll
    for (int j = 0; j < 8; ++j) acc[j] += w0 * b2f(xr[lane + 64*j]);
  }
  #pragma unroll
  for (int j = 0; j < 8; ++j)
    gat[(size_t)i*512 + lane + 64*j] = acc[j] + b_gat[lane + 64*j];
}

// ---------------- conv + silu ----------------
__global__ void conv_silu(const unsigned short* __restrict__ xzb,
                          const float* __restrict__ w_conv, const float* __restrict__ b_conv,
                          float* __restrict__ xc, unsigned short* __restrict__ xcb){
  int r = blockIdx.x;
  int c = blockIdx.y*256 + threadIdx.x;
  int t = r & (LL - 1);
  float acc = b_conv[c];
  #pragma unroll
  for (int k = 0; k < 4; ++k){
    int tt = t + k - 3;
    if (tt >= 0) acc += b2f(xzb[(size_t)(r + k - 3)*1024 + c]) * w_conv[c*4 + k];
  }
  float s = acc / (1.f + expf(-acc));
  xc[(size_t)r*512 + c] = s;
  xcb[(size_t)r*512 + c] = f2b(s);
}

// ---------------- SSM scan: thread per (b,d,s) ----------------
__global__ __launch_bounds__(256)
void ssm_scan(const float* __restrict__ dt, const float* __restrict__ xc,
              const float* __restrict__ BC, const unsigned short* __restrict__ xzb,
              const float* __restrict__ A_log, const float* __restrict__ D_p,
              unsigned short* __restrict__ yfb){
  int s  = threadIdx.x & 15;
  int dl = threadIdx.x >> 4;             // 0..15
  int b  = blockIdx.x >> 5;              // 0..7
  int d  = (blockIdx.x & 31)*16 + dl;    // 0..511
  float A = -expf(A_log[d*16 + s]);
  float Dp = D_p[d];
  float h = 0.f;
  size_t rbase = (size_t)b * LL;
  for (int t = 0; t < LL; ++t){
    size_t r = rbase + t;
    float dtv = dt[r*512 + d];
    float xv  = xc[r*512 + d];
    float Bv  = BC[r*32 + s];
    float Cv  = BC[r*32 + 16 + s];
    float a = expf(dtv * A);
    h = h*a + (dtv*xv)*Bv;
    float y = h * Cv;
    y += __shfl_xor(y, 1);
    y += __shfl_xor(y, 2);
    y += __shfl_xor(y, 4);
    y += __shfl_xor(y, 8);
    if (s == 0){
      float z  = b2f(xzb[r*1024 + 512 + d]);
      float sz = z / (1.f + expf(-z));
      float yf = (y + Dp*xv) * sz;
      yfb[r*512 + d] = f2b(yf);
    }
  }
}

// ---------------- column stats (sum, sumsq) ----------------
__global__ void colstats(const float* __restrict__ X, float* __restrict__ sums, float* __restrict__ sqs){
  int c0 = threadIdx.x;
  int row0 = blockIdx.x * 128;
  float s0=0,q0=0,s1=0,q1=0;
  for (int i = 0; i < 128; ++i){
    const float* rp = X + (size_t)(row0+i)*512;
    float a = rp[c0], b = rp[c0+256];
    s0 += a; q0 += a*a; s1 += b; q1 += b*b;
  }
  atomicAdd(&sums[c0], s0);      atomicAdd(&sqs[c0], q0);
  atomicAdd(&sums[c0+256], s1);  atomicAdd(&sqs[c0+256], q1);
}

// out0 = BN(gat)*g1+be1 + BN(h2)*g2+be2  (f32 + bf16)
__global__ void combine_out0(const float* __restrict__ gat, const float* __restrict__ h2,
                             const float* __restrict__ s1, const float* __restrict__ q1,
                             const float* __restrict__ s2, const float* __restrict__ q2,
                             const float* __restrict__ g1, const float* __restrict__ be1,
                             const float* __restrict__ g2, const float* __restrict__ be2,
                             float* __restrict__ out0, unsigned short* __restrict__ out0b){
  int t = threadIdx.x;
  int row0 = blockIdx.x * 128;
  const float invN = 1.f/16384.f;
  float sc1[2], sc2[2], off[2];
  #pragma unroll
  for (int h = 0; h < 2; ++h){
    int c = t + h*256;
    float m1 = s1[c]*invN, v1 = q1[c]*invN - m1*m1;
    float m2 = s2[c]*invN, v2 = q2[c]*invN - m2*m2;
    float a1 = rsqrtf(v1 + 1e-5f) * g1[c];
    float a2 = rsqrtf(v2 + 1e-5f) * g2[c];
    sc1[h] = a1; sc2[h] = a2;
    off[h] = be1[c] + be2[c] - m1*a1 - m2*a2;
  }
  for (int i = 0; i < 128; ++i){
    size_t ro = (size_t)(row0+i)*512;
    #pragma unroll
    for (int h = 0; h < 2; ++h){
      int c = t + h*256;
      float v = gat[ro+c]*sc1[h] + h2[ro+c]*sc2[h] + off[h];
      out0[ro+c] = v;
      out0b[ro+c] = f2b(v);
    }
  }
}

// out2 = relu(BN(out1)*g3+be3); per-batch column sums -> poolsum
__global__ void out2_pool(const float* __restrict__ out1,
                          const float* __restrict__ s3, const float* __restrict__ q3,
                          const float* __restrict__ g3, const float* __restrict__ be3,
                          float* __restrict__ poolsum){
  int t = threadIdx.x;
  int row0 = blockIdx.x * 128;
  int bidx = row0 / LL;
  const float invN = 1.f/16384.f;
  float sc[2], off[2], acc[2] = {0.f, 0.f};
  #pragma unroll
  for (int h = 0; h < 2; ++h){
    int c = t + h*256;
    float m = s3[c]*invN, v = q3[c]*invN - m*m;
    float a = rsqrtf(v + 1e-5f) * g3[c];
    sc[h] = a; off[h] = be3[c] - m*a;
  }
  for (int i = 0; i < 128; ++i){
    size_t ro = (size_t)(row0+i)*512;
    #pragma unroll
    for (int h = 0; h < 2; ++h){
      int c = t + h*256;
      float v = fmaxf(out1[ro+c]*sc[h] + off[h], 0.f);
      acc[h] += v;
    }
  }
  atomicAdd(&poolsum[bidx*512 + t], acc[0]);
  atomicAdd(&poolsum[bidx*512 + t + 256], acc[1]);
}

// final head MLP: one block per batch row
__global__ __launch_bounds__(256)
void head(const float* __restrict__ poolsum,
          const float* __restrict__ Wf1, const float* __restrict__ bf1,
          const float* __restrict__ Wf2, const float* __restrict__ bf2,
          const float* __restrict__ Wf3, const float* __restrict__ bf3,
          float* __restrict__ dout){
  int r = blockIdx.x, t = threadIdx.x;
  __shared__ float pool[512];
  __shared__ float h1s[256];
  __shared__ float h2s[128];
  for (int i = t; i < 512; i += 256){
    float v = poolsum[r*512 + i] * (1.f/2048.f);
    pool[i] = v;
    dout[8 + r*512 + i] = v;
  }
  __syncthreads();
  {
    float a = bf1[t];
    for (int k = 0; k < 512; ++k) a += pool[k] * Wf1[(size_t)k*256 + t];
    h1s[t] = fmaxf(a, 0.f);
  }
  __syncthreads();
  if (t < 128){
    float a = bf2[t];
    for (int k = 0; k < 256; ++k) a += h1s[k] * Wf2[(size_t)k*128 + t];
    h2s[t] = fmaxf(a, 0.f);
  }
  __syncthreads();
  if (t == 0){
    float a = bf3[0];
    for (int k = 0; k < 128; ++k) a += h2s[k] * Wf3[k];
    dout[r] = a;
  }
}

// ---------------- host ----------------
extern "C" void kernel_launch(void* const* d_in, const int* in_sizes, int n_in,
                              void* d_out, int out_size, void* d_ws, size_t ws_size,
                              hipStream_t stream){
  const float* x      = (const float*)d_in[0];
  const int*   ei     = (const int*)d_in[1];
  const float* W_uni  = (const float*)d_in[5];
  const float* b_uni  = (const float*)d_in[6];
  const float* W_gat  = (const float*)d_in[10];
  const float* att_s  = (const float*)d_in[11];
  const float* att_d  = (const float*)d_in[12];
  const float* b_gat  = (const float*)d_in[13];
  const float* g1     = (const float*)d_in[14];
  const float* be1    = (const float*)d_in[15];
  const float* g2     = (const float*)d_in[16];
  const float* be2    = (const float*)d_in[17];
  const float* g3     = (const float*)d_in[18];
  const float* be3    = (const float*)d_in[19];
  const float* W_in   = (const float*)d_in[20];
  const float* w_conv = (const float*)d_in[21];
  const float* b_conv = (const float*)d_in[22];
  const float* W_xp   = (const float*)d_in[23];
  const float* W_dt   = (const float*)d_in[24];
  const float* b_dt   = (const float*)d_in[25];
  const float* A_log  = (const float*)d_in[26];
  const float* D_p    = (const float*)d_in[27];
  const float* W_out  = (const float*)d_in[28];
  const float* W_m1   = (const float*)d_in[29];
  const float* b_m1   = (const float*)d_in[30];
  const float* W_m2   = (const float*)d_in[31];
  const float* b_m2   = (const float*)d_in[32];
  const float* Wf1    = (const float*)d_in[33];
  const float* bf1    = (const float*)d_in[34];
  const float* Wf2    = (const float*)d_in[35];
  const float* bf2    = (const float*)d_in[36];
  const float* Wf3    = (const float*)d_in[37];
  const float* bf3    = (const float*)d_in[38];
  float* dout = (float*)d_out;

  char* base = (char*)d_ws;
  size_t off = 0;
  auto alloc = [&](size_t b){ size_t r = off; off += (b + 255) & ~(size_t)255; return r; };

  size_t oR1    = alloc((size_t)NN*1024*2);   // Xb -> xzb -> out1 (33.5MB each, aliased)
  size_t oH0b   = alloc((size_t)NN*512*2);    // h0b bf16
  size_t oWuniT = alloc(512*1024*2);
  size_t oWgatT = alloc(512*512*2);
  size_t oWinT  = alloc(1024*512*2);
  size_t oWfusT = alloc(512*512*2);
  size_t oWbcT  = alloc(128*512*2);
  size_t oWoutT = alloc(512*512*2);
  size_t oWm1T  = alloc(1024*512*2);
  size_t oWm2T  = alloc(512*1024*2);
  size_t oBuni  = alloc(512*4);
  size_t oXh    = alloc((size_t)NN*512*2);    // xh bf16 -> yfb bf16
  size_t oAs    = alloc(NN*4);
  size_t oAd    = alloc(NN*4);
  size_t oCnt   = alloc(NN*4);
  size_t oCur   = alloc(NN*4);
  size_t oOff   = alloc((NN+1)*4);
  size_t oSrcs  = alloc((size_t)EE*4);
  size_t oAlph  = alloc((size_t)EE*4);
  size_t oGat   = alloc((size_t)NN*512*4);    // gat f32 -> mlp1b bf16
  size_t oXc    = alloc((size_t)NN*512*4);    // xc f32 -> out0 f32
  size_t oXcb   = alloc((size_t)NN*512*2);    // xcb bf16 -> out0b bf16
  size_t oDt    = alloc((size_t)NN*512*4);    // dt f32 -> h2raw f32
  size_t oBC    = alloc((size_t)NN*32*4);
  size_t oStats = alloc(6*512*4);             // s1,q1,s2,q2,s3,q3
  size_t oPool  = alloc(8*512*4);

  short* Xb   = (short*)(base + oR1);
  unsigned short* xzb = (unsigned short*)(base + oR1);
  float* out1 = (float*)(base + oR1);
  unsigned short* h0b = (unsigned short*)(base + oH0b);
  short* WuniT = (short*)(base + oWuniT);
  short* WgatT = (short*)(base + oWgatT);
  short* WinT  = (short*)(base + oWinT);
  short* WfusT = (short*)(base + oWfusT);
  short* WbcT  = (short*)(base + oWbcT);
  short* WoutT = (short*)(base + oWoutT);
  short* Wm1T  = (short*)(base + oWm1T);
  short* Wm2T  = (short*)(base + oWm2T);
  float* buniP = (float*)(base + oBuni);
  unsigned short* xh  = (unsigned short*)(base + oXh);
  unsigned short* yfb = (unsigned short*)(base + oXh);
  float* a_s = (float*)(base + oAs);
  float* a_d = (float*)(base + oAd);
  int* cnt = (int*)(base + oCnt);
  int* cur = (int*)(base + oCur);
  int* offs = (int*)(base + oOff);
  int* srcs = (int*)(base + oSrcs);
  float* alphas = (float*)(base + oAlph);
  float* gat = (float*)(base + oGat);
  unsigned short* mlp1b = (unsigned short*)(base + oGat);
  float* xc = (float*)(base + oXc);
  float* out0 = (float*)(base + oXc);
  unsigned short* xcb  = (unsigned short*)(base + oXcb);
  unsigned short* out0b = (unsigned short*)(base + oXcb);
  float* dt = (float*)(base + oDt);
  float* h2raw = (float*)(base + oDt);
  float* BC = (float*)(base + oBC);
  float* s1 = (float*)(base + oStats);
  float* q1 = s1 + 512;
  float* s2 = q1 + 512;
  float* q2 = s2 + 512;
  float* s3 = q2 + 512;
  float* q3 = s3 + 512;
  float* poolsum = (float*)(base + oPool);

  // zero the accumulators
  hipMemsetAsync(cnt, 0, NN*4, stream);
  hipMemsetAsync(s1, 0, 6*512*4, stream);
  hipMemsetAsync(poolsum, 0, 8*512*4, stream);

  // prep: convert/transpose weights, convert x, fuse W_xp@W_dt
  transposeW<<<(512*1024+255)/256, 256, 0, stream>>>(W_uni, WuniT, 1024, 496, 512, 496, 0);
  transposeW<<<(512*512+255)/256, 256, 0, stream>>>(W_gat, WgatT, 512, 512, 512, 512, 0);
  transposeW<<<(1024*512+255)/256, 256, 0, stream>>>(W_in, WinT, 512, 1024, 1024, 1024, 0);
  transposeW<<<(128*512+255)/256, 256, 0, stream>>>(W_xp, WbcT, 512, 32, 128, 64, 32);
  transposeW<<<(512*512+255)/256, 256, 0, stream>>>(W_out, WoutT, 512, 512, 512, 512, 0);
  transposeW<<<(1024*512+255)/256, 256, 0, stream>>>(W_m1, Wm1T, 512, 1024, 1024, 1024, 0);
  transposeW<<<(512*1024+255)/256, 256, 0, stream>>>(W_m2, Wm2T, 1024, 512, 512, 512, 0);
  fuse_wdt<<<(512*512+255)/256, 256, 0, stream>>>(W_xp, W_dt, WfusT);
  pad_bias<<<2, 256, 0, stream>>>(b_uni, buniP);
  conv_x<<<(NN*1024+255)/256, 256, 0, stream>>>(x, Xb);

  dim3 g4(128, 4), g8(128, 8), g1b(128, 1);
  // h0 = [x@W_uni + b_uni | pe]
  gemm_bt<<<g4, 256, 0, stream>>>(Xb, WuniT, nullptr, h0b, buniP, nullptr, 1024, 512, 0);
  pe_fill<<<(NN+255)/256, 256, 0, stream>>>(x, h0b);
  // xh = h0 @ W_gat  (bf16)
  gemm_bt<<<g4, 256, 0, stream>>>((const short*)h0b, WgatT, nullptr, xh, nullptr, nullptr, 512, 512, 0);
  att_proj<<<NN/4, 256, 0, stream>>>(xh, att_s, att_d, a_s, a_d);
  // GAT
  gat_hist<<<EE/256, 256, 0, stream>>>(ei, cnt);
  gat_prefix<<<1, 256, 0, stream>>>(cnt, offs, cur);
  gat_scatter<<<EE/256, 256, 0, stream>>>(ei, a_s, a_d, cur, srcs, alphas);
  gat_agg<<<NN/4, 256, 0, stream>>>(offs, srcs, alphas, xh, a_s, a_d, b_gat, gat);
  colstats<<<128, 256, 0, stream>>>(gat, s1, q1);
  // Mamba path
  gemm_bt<<<g8, 256, 0, stream>>>((const short*)h0b, WinT, nullptr, xzb, nullptr, nullptr, 512, 1024, 0);
  {
    dim3 gc(NN, 2);
    conv_silu<<<gc, 256, 0, stream>>>(xzb, w_conv, b_conv, xc, xcb);
  }
  gemm_bt<<<g4, 256, 0, stream>>>((const short*)xcb, WfusT, dt, nullptr, b_dt, nullptr, 512, 512, 2);
  gemm_bt<<<g1b, 256, 0, stream>>>((const short*)xcb, WbcT, BC, nullptr, nullptr, nullptr, 512, 32, 0);
  ssm_scan<<<256, 256, 0, stream>>>(dt, xc, BC, xzb, A_log, D_p, yfb);
  gemm_bt<<<g4, 256, 0, stream>>>((const short*)yfb, WoutT, h2raw, nullptr, nullptr, nullptr, 512, 512, 0);
  colstats<<<128, 256, 0, stream>>>(h2raw, s2, q2);
  // combine + MLP residual
  combine_out0<<<128, 256, 0, stream>>>(gat, h2raw, s1, q1, s2, q2, g1, be1, g2, be2, out0, out0b);
  gemm_bt<<<g8, 256, 0, stream>>>((const short*)out0b, Wm1T, nullptr, mlp1b, b_m1, nullptr, 512, 1024, 1);
  gemm_bt<<<g4, 256, 0, stream>>>((const short*)mlp1b, Wm2T, out1, nullptr, b_m2, out0, 1024, 512, 0);
  colstats<<<128, 256, 0, stream>>>(out1, s3, q3);
  out2_pool<<<128, 256, 0, stream>>>(out1, s3, q3, g3, be3, poolsum);
  head<<<8, 256, 0, stream>>>(poolsum, Wf1, bf1, Wf2, bf2, Wf3, bf3, dout);
}

// Round 4
// 1116.955 us; speedup vs baseline: 2.1731x; 2.1731x over previous
//
#include <hip/hip_runtime.h>
#include <math.h>

#define NN 16384
#define CD 512
#define EE 262144
#define LL 2048
#define NCK 32   // time chunks per batch
#define TC 64    // steps per chunk

typedef __attribute__((ext_vector_type(8))) short short8;
typedef __attribute__((ext_vector_type(4))) float floatx4;

__device__ __forceinline__ unsigned short f2b(float f){
  unsigned int u = __float_as_uint(f);
  unsigned int r = (u + 0x7fffu + ((u>>16)&1u)) >> 16;
  return (unsigned short)r;
}
__device__ __forceinline__ float b2f(unsigned short h){
  return __uint_as_float(((unsigned int)h)<<16);
}

// ---------------- prep kernels ----------------

// W: K x Nsub (row pitch `pitch`, col offset col0) -> Bt: Npad x K bf16 (zero-padded rows)
__global__ void transposeW(const float* __restrict__ W, short* __restrict__ Bt,
                           int K, int Nsub, int Npad, int pitch, int col0){
  int idx = blockIdx.x*256 + threadIdx.x;
  if (idx >= Npad*K) return;
  int n = idx / K, k = idx - n*K;
  float v = (n < Nsub) ? W[(size_t)k*pitch + col0 + n] : 0.f;
  Bt[idx] = (short)f2b(v);
}

// Wfused^T[j][i] = sum_r W_xp[i,r]*W_dt[r,j]  (512x512 bf16, Bt layout)
__global__ void fuse_wdt(const float* __restrict__ W_xp, const float* __restrict__ W_dt,
                         short* __restrict__ Wft){
  int idx = blockIdx.x*256 + threadIdx.x;   // 512*512
  if (idx >= 512*512) return;
  int i = idx & 511;      // input channel (k-dim)
  int j = idx >> 9;       // output channel
  float a = 0.f;
  #pragma unroll 8
  for (int r = 0; r < 32; ++r) a += W_xp[(size_t)i*64 + r] * W_dt[(size_t)r*512 + j];
  Wft[idx] = (short)f2b(a);
}

__global__ void pad_bias(const float* __restrict__ b, float* __restrict__ out){
  int i = blockIdx.x*256 + threadIdx.x;
  if (i < 512) out[i] = (i < 496) ? b[i] : 0.f;
}

// x (16384 x 1026) cols 2..1025 -> Xb bf16 (16384 x 1024)
__global__ void conv_x(const float* __restrict__ x, short* __restrict__ Xb){
  int idx = blockIdx.x*256 + threadIdx.x;
  if (idx >= NN*1024) return;
  int r = idx >> 10, c = idx & 1023;
  Xb[idx] = (short)f2b(x[(size_t)r*1026 + 2 + c]);
}

// positional encodings into h0b cols 496..511
__global__ void pe_fill(const float* __restrict__ x, unsigned short* __restrict__ h0b){
  int r = blockIdx.x*256 + threadIdx.x;
  if (r >= NN) return;
  float p0 = x[(size_t)r*1026 + 0], p1 = x[(size_t)r*1026 + 1];
  const float dn[4] = {1.f, 10.f, 100.f, 1000.f};
  unsigned short* o = h0b + (size_t)r*512 + 496;
  #pragma unroll
  for (int q = 0; q < 4; ++q){
    o[2*q]     = f2b(sinf(p0/dn[q]));
    o[2*q+1]   = f2b(cosf(p0/dn[q]));
    o[8+2*q]   = f2b(sinf(p1/dn[q]));
    o[8+2*q+1] = f2b(cosf(p1/dn[q]));
  }
}

// ---------------- GEMM (A MxK bf16 row-major, Bt NpadxK bf16 row-major) ----------------
// 128x128 tile, 4 waves (2x2), each wave 64x64 via 4x4 mfma_f32_16x16x32_bf16 frags.
// Staging via global_load_lds width=16 (m97 pattern): wave w stages rows
// [w*32, w*32+32) of As and Bs; LDS dest is wave-uniform base + lane*16B which
// linearly matches the row-major [128][32] tile (lane l -> row +(l>>2), col (l&3)*8).
#define GLDS(g, l) __builtin_amdgcn_global_load_lds((const __attribute__((address_space(1))) void*)(g), (__attribute__((address_space(3))) void*)(l), 16, 0, 0)

__global__ __launch_bounds__(256)
void gemm_bt(const short* __restrict__ A, const short* __restrict__ Bt,
             float* __restrict__ Cf, unsigned short* __restrict__ Cb,
             const float* __restrict__ bias, const float* __restrict__ resid,
             int K, int Nvalid, int epi){
  __shared__ __align__(16) short As[128*32];
  __shared__ __align__(16) short Bs[128*32];
  int tid = threadIdx.x;
  int m0 = blockIdx.x * 128;
  int n0 = blockIdx.y * 128;
  int lane = tid & 63, wave = tid >> 6;
  int wm = wave >> 1, wn = wave & 1;
  int lr = lane & 15, lk = lane >> 4;

  floatx4 acc[4][4];
  #pragma unroll
  for (int m = 0; m < 4; ++m)
    #pragma unroll
    for (int n = 0; n < 4; ++n) acc[m][n] = (floatx4)0.f;

  int wrow = wave * 32;          // wave's 32-row stripe of the tile
  int srow = lane >> 2;          // 0..15
  int scol = (lane & 3) * 8;     // 0,8,16,24 (elements)

  const short* gA0 = A  + (size_t)(m0 + wrow + srow)*K      + scol;
  const short* gA1 = A  + (size_t)(m0 + wrow + 16 + srow)*K + scol;
  const short* gB0 = Bt + (size_t)(n0 + wrow + srow)*K      + scol;
  const short* gB1 = Bt + (size_t)(n0 + wrow + 16 + srow)*K + scol;

  for (int k0 = 0; k0 < K; k0 += 32){
    __syncthreads();
    GLDS(gA0 + k0, &As[wrow*32]);
    GLDS(gA1 + k0, &As[(wrow+16)*32]);
    GLDS(gB0 + k0, &Bs[wrow*32]);
    GLDS(gB1 + k0, &Bs[(wrow+16)*32]);
    __syncthreads();
    short8 af[4], bf[4];
    #pragma unroll
    for (int m = 0; m < 4; ++m) af[m] = *(const short8*)&As[(wm*64 + m*16 + lr)*32 + lk*8];
    #pragma unroll
    for (int n = 0; n < 4; ++n) bf[n] = *(const short8*)&Bs[(wn*64 + n*16 + lr)*32 + lk*8];
    #pragma unroll
    for (int m = 0; m < 4; ++m)
      #pragma unroll
      for (int n = 0; n < 4; ++n)
        acc[m][n] = __builtin_amdgcn_mfma_f32_16x16x32_bf16(af[m], bf[n], acc[m][n], 0, 0, 0);
  }

  #pragma unroll
  for (int m = 0; m < 4; ++m){
    #pragma unroll
    for (int n = 0; n < 4; ++n){
      int col = n0 + wn*64 + n*16 + lr;
      if (col < Nvalid){
        #pragma unroll
        for (int r = 0; r < 4; ++r){
          int row = m0 + wm*64 + m*16 + lk*4 + r;
          float v = acc[m][n][r];
          if (bias)  v += bias[col];
          if (resid) v += resid[(size_t)row*Nvalid + col];
          if (epi == 1) v = fmaxf(v, 0.f);
          else if (epi == 2) v = (v > 20.f) ? v : log1pf(expf(v));
          size_t o = (size_t)row*Nvalid + col;
          if (Cf) Cf[o] = v;
          if (Cb) Cb[o] = f2b(v);
        }
      }
    }
  }
}

// ---------------- attention scalars ----------------
__global__ void att_proj(const unsigned short* __restrict__ xh,
                         const float* __restrict__ att_src, const float* __restrict__ att_dst,
                         float* __restrict__ a_s, float* __restrict__ a_d){
  int wave = threadIdx.x >> 6, lane = threadIdx.x & 63;
  int r = blockIdx.x*4 + wave;
  const unsigned short* xr = xh + (size_t)r*512;
  float ps = 0.f, pd = 0.f;
  #pragma unroll
  for (int j = 0; j < 8; ++j){
    float v = b2f(xr[lane + 64*j]);
    ps += v * att_src[lane + 64*j];
    pd += v * att_dst[lane + 64*j];
  }
  #pragma unroll
  for (int m = 32; m >= 1; m >>= 1){ ps += __shfl_xor(ps, m); pd += __shfl_xor(pd, m); }
  if (lane == 0){ a_s[r] = ps; a_d[r] = pd; }
}

// ---------------- GAT bucketing ----------------
__global__ void gat_hist(const int* __restrict__ ei, int* __restrict__ cnt){
  int e = blockIdx.x*256 + threadIdx.x;
  if (e < EE) atomicAdd(&cnt[ei[EE + e]], 1);
}

__global__ void gat_prefix(const int* __restrict__ cnt, int* __restrict__ offsets, int* __restrict__ cursor){
  __shared__ int part[256];
  int t = threadIdx.x;
  int s = 0;
  for (int i = 0; i < 64; ++i) s += cnt[t*64 + i];
  part[t] = s;
  __syncthreads();
  for (int off = 1; off < 256; off <<= 1){
    int v = (t >= off) ? part[t - off] : 0;
    __syncthreads();
    part[t] += v;
    __syncthreads();
  }
  int run = part[t] - s;   // exclusive base
  for (int i = 0; i < 64; ++i){
    int c = cnt[t*64 + i];
    offsets[t*64 + i] = run;
    cursor[t*64 + i]  = run;
    run += c;
  }
  if (t == 255) offsets[NN] = run;
}

__global__ void gat_scatter(const int* __restrict__ ei, const float* __restrict__ a_s,
                            const float* __restrict__ a_d, int* __restrict__ cursor,
                            int* __restrict__ srcs, float* __restrict__ alphas){
  int e = blockIdx.x*256 + threadIdx.x;
  if (e >= EE) return;
  int sN = ei[e], dN = ei[EE + e];
  int p = atomicAdd(&cursor[dN], 1);
  srcs[p] = sN;
  float al = a_s[sN] + a_d[dN];
  alphas[p] = (al > 0.f) ? al : 0.2f*al;
}

// one wave per dst node: softmax over in-edges (+self loop), gather-weighted sum
__global__ __launch_bounds__(256)
void gat_agg(const int* __restrict__ offsets, const int* __restrict__ srcs,
             const float* __restrict__ alphas, const unsigned short* __restrict__ xh,
             const float* __restrict__ a_s, const float* __restrict__ a_d,
             const float* __restrict__ b_gat, float* __restrict__ gat){
  int wave = threadIdx.x >> 6, lane = threadIdx.x & 63;
  int i = blockIdx.x*4 + wave;
  int beg = offsets[i], end = offsets[i+1];
  float asd = a_s[i] + a_d[i];
  float al0 = (asd > 0.f) ? asd : 0.2f*asd;
  float mx = al0;
  for (int p = beg + lane; p < end; p += 64) mx = fmaxf(mx, alphas[p]);
  #pragma unroll
  for (int m = 32; m >= 1; m >>= 1) mx = fmaxf(mx, __shfl_xor(mx, m));
  float se = 0.f;
  for (int p = beg + lane; p < end; p += 64) se += expf(alphas[p] - mx);
  #pragma unroll
  for (int m = 32; m >= 1; m >>= 1) se += __shfl_xor(se, m);
  float den = se + expf(al0 - mx);
  float inv = 1.f/(den + 1e-16f);
  float acc[8] = {0,0,0,0,0,0,0,0};
  for (int p = beg; p < end; ++p){
    float w = expf(alphas[p] - mx) * inv;
    const unsigned short* xr = xh + (size_t)srcs[p]*512;
    #pragma unroll
    for (int j = 0; j < 8; ++j) acc[j] += w * b2f(xr[lane + 64*j]);
  }
  {
    float w0 = expf(al0 - mx) * inv;
    const unsigned short* xr = xh + (size_t)i*512;
    #pragma unroll
    for (int j = 0; j < 8; ++j) acc[j] += w0 * b2f(xr[lane + 64*j]);
  }
  #pragma unroll
  for (int j = 0; j < 8; ++j)
    gat[(size_t)i*512 + lane + 64*j] = acc[j] + b_gat[lane + 64*j];
}

// ---------------- conv + silu ----------------
__global__ void conv_silu(const unsigned short* __restrict__ xzb,
                          const float* __restrict__ w_conv, const float* __restrict__ b_conv,
                          float* __restrict__ xc, unsigned short* __restrict__ xcb){
  int r = blockIdx.x;
  int c = blockIdx.y*256 + threadIdx.x;
  int t = r & (LL - 1);
  float acc = b_conv[c];
  #pragma unroll
  for (int k = 0; k < 4; ++k){
    int tt = t + k - 3;
    if (tt >= 0) acc += b2f(xzb[(size_t)(r + k - 3)*1024 + c]) * w_conv[c*4 + k];
  }
  float s = acc / (1.f + expf(-acc));
  xc[(size_t)r*512 + c] = s;
  xcb[(size_t)r*512 + c] = f2b(s);
}

// ---------------- SSM chunked parallel scan ----------------
// Pass 1: per-chunk local scan from h=0; emit P=prod(a), H=local final h.
// Layout of Pc/Hc: [b][chunk][d][s]  (chunk stride = 512*16)
__global__ __launch_bounds__(256)
void ssm_scan1(const float* __restrict__ dt, const float* __restrict__ xc,
               const float* __restrict__ BC, const float* __restrict__ A_log,
               float* __restrict__ Pc, float* __restrict__ Hc){
  int s  = threadIdx.x & 15;
  int dl = threadIdx.x >> 4;             // 0..15
  int bc = blockIdx.x;                   // b*NCK + chunk
  int b  = bc >> 5;
  int ck = bc & (NCK - 1);
  int d  = blockIdx.y*16 + dl;
  float A = -expf(A_log[d*16 + s]);
  float h = 0.f, P = 1.f;
  size_t r = (size_t)b*LL + (size_t)ck*TC;
  for (int t = 0; t < TC; ++t, ++r){
    float dtv = dt[r*512 + d];
    float xv  = xc[r*512 + d];
    float Bv  = BC[r*32 + s];
    float a = expf(dtv * A);
    h = h*a + (dtv*xv)*Bv;
    P *= a;
  }
  size_t idx = ((size_t)bc*512 + d)*16 + s;
  Pc[idx] = P;
  Hc[idx] = h;
}

// Carry pass: one thread per (b,d,s) stripe; sequential over 32 chunks.
// In-place: Hc[c] is overwritten with the chunk's INPUT carry.
__global__ void ssm_carry(const float* __restrict__ Pc, float* __restrict__ Hc){
  int gid = blockIdx.x*256 + threadIdx.x;   // 0..65535
  int b  = gid >> 13;                       // 512*16 = 8192 stripes per batch
  int ds = gid & 8191;
  size_t idx = ((size_t)b*NCK)*8192 + ds;
  float carry = 0.f;
  for (int c = 0; c < NCK; ++c){
    float P = Pc[idx], H = Hc[idx];
    Hc[idx] = carry;
    carry = H + P*carry;
    idx += 8192;
  }
}

// Pass 2: re-scan each chunk from its true carry-in; emit gated output.
__global__ __launch_bounds__(256)
void ssm_scan2(const float* __restrict__ dt, const float* __restrict__ xc,
               const float* __restrict__ BC, const unsigned short* __restrict__ xzb,
               const float* __restrict__ A_log, const float* __restrict__ D_p,
               const float* __restrict__ Cin, unsigned short* __restrict__ yfb){
  int s  = threadIdx.x & 15;
  int dl = threadIdx.x >> 4;
  int bc = blockIdx.x;
  int b  = bc >> 5;
  int ck = bc & (NCK - 1);
  int d  = blockIdx.y*16 + dl;
  float A = -expf(A_log[d*16 + s]);
  float Dp = D_p[d];
  size_t idx = ((size_t)bc*512 + d)*16 + s;
  float h = Cin[idx];
  size_t r = (size_t)b*LL + (size_t)ck*TC;
  for (int t = 0; t < TC; ++t, ++r){
    float dtv = dt[r*512 + d];
    float xv  = xc[r*512 + d];
    float Bv  = BC[r*32 + s];
    float Cv  = BC[r*32 + 16 + s];
    float a = expf(dtv * A);
    h = h*a + (dtv*xv)*Bv;
    float y = h * Cv;
    y += __shfl_xor(y, 1);
    y += __shfl_xor(y, 2);
    y += __shfl_xor(y, 4);
    y += __shfl_xor(y, 8);
    if (s == 0){
      float z  = b2f(xzb[r*1024 + 512 + d]);
      float sz = z / (1.f + expf(-z));
      yfb[r*512 + d] = f2b((y + Dp*xv) * sz);
    }
  }
}

// ---------------- column stats (sum, sumsq) ----------------
__global__ void colstats(const float* __restrict__ X, float* __restrict__ sums, float* __restrict__ sqs){
  int c0 = threadIdx.x;
  int row0 = blockIdx.x * 128;
  float s0=0,q0=0,s1=0,q1=0;
  for (int i = 0; i < 128; ++i){
    const float* rp = X + (size_t)(row0+i)*512;
    float a = rp[c0], b = rp[c0+256];
    s0 += a; q0 += a*a; s1 += b; q1 += b*b;
  }
  atomicAdd(&sums[c0], s0);      atomicAdd(&sqs[c0], q0);
  atomicAdd(&sums[c0+256], s1);  atomicAdd(&sqs[c0+256], q1);
}

// out0 = BN(gat)*g1+be1 + BN(h2)*g2+be2  (f32 + bf16)
__global__ void combine_out0(const float* __restrict__ gat, const float* __restrict__ h2,
                             const float* __restrict__ s1, const float* __restrict__ q1,
                             const float* __restrict__ s2, const float* __restrict__ q2,
                             const float* __restrict__ g1, const float* __restrict__ be1,
                             const float* __restrict__ g2, const float* __restrict__ be2,
                             float* __restrict__ out0, unsigned short* __restrict__ out0b){
  int t = threadIdx.x;
  int row0 = blockIdx.x * 128;
  const float invN = 1.f/16384.f;
  float sc1[2], sc2[2], off[2];
  #pragma unroll
  for (int h = 0; h < 2; ++h){
    int c = t + h*256;
    float m1 = s1[c]*invN, v1 = q1[c]*invN - m1*m1;
    float m2 = s2[c]*invN, v2 = q2[c]*invN - m2*m2;
    float a1 = rsqrtf(v1 + 1e-5f) * g1[c];
    float a2 = rsqrtf(v2 + 1e-5f) * g2[c];
    sc1[h] = a1; sc2[h] = a2;
    off[h] = be1[c] + be2[c] - m1*a1 - m2*a2;
  }
  for (int i = 0; i < 128; ++i){
    size_t ro = (size_t)(row0+i)*512;
    #pragma unroll
    for (int h = 0; h < 2; ++h){
      int c = t + h*256;
      float v = gat[ro+c]*sc1[h] + h2[ro+c]*sc2[h] + off[h];
      out0[ro+c] = v;
      out0b[ro+c] = f2b(v);
    }
  }
}

// out2 = relu(BN(out1)*g3+be3); per-batch column sums -> poolsum
__global__ void out2_pool(const float* __restrict__ out1,
                          const float* __restrict__ s3, const float* __restrict__ q3,
                          const float* __restrict__ g3, const float* __restrict__ be3,
                          float* __restrict__ poolsum){
  int t = threadIdx.x;
  int row0 = blockIdx.x * 128;
  int bidx = row0 / LL;
  const float invN = 1.f/16384.f;
  float sc[2], off[2], acc[2] = {0.f, 0.f};
  #pragma unroll
  for (int h = 0; h < 2; ++h){
    int c = t + h*256;
    float m = s3[c]*invN, v = q3[c]*invN - m*m;
    float a = rsqrtf(v + 1e-5f) * g3[c];
    sc[h] = a; off[h] = be3[c] - m*a;
  }
  for (int i = 0; i < 128; ++i){
    size_t ro = (size_t)(row0+i)*512;
    #pragma unroll
    for (int h = 0; h < 2; ++h){
      int c = t + h*256;
      float v = fmaxf(out1[ro+c]*sc[h] + off[h], 0.f);
      acc[h] += v;
    }
  }
  atomicAdd(&poolsum[bidx*512 + t], acc[0]);
  atomicAdd(&poolsum[bidx*512 + t + 256], acc[1]);
}

// final head MLP: one block per batch row
__global__ __launch_bounds__(256)
void head(const float* __restrict__ poolsum,
          const float* __restrict__ Wf1, const float* __restrict__ bf1,
          const float* __restrict__ Wf2, const float* __restrict__ bf2,
          const float* __restrict__ Wf3, const float* __restrict__ bf3,
          float* __restrict__ dout){
  int r = blockIdx.x, t = threadIdx.x;
  __shared__ float pool[512];
  __shared__ float h1s[256];
  __shared__ float h2s[128];
  for (int i = t; i < 512; i += 256){
    float v = poolsum[r*512 + i] * (1.f/2048.f);
    pool[i] = v;
    dout[8 + r*512 + i] = v;
  }
  __syncthreads();
  {
    float a = bf1[t];
    for (int k = 0; k < 512; ++k) a += pool[k] * Wf1[(size_t)k*256 + t];
    h1s[t] = fmaxf(a, 0.f);
  }
  __syncthreads();
  if (t < 128){
    float a = bf2[t];
    for (int k = 0; k < 256; ++k) a += h1s[k] * Wf2[(size_t)k*128 + t];
    h2s[t] = fmaxf(a, 0.f);
  }
  __syncthreads();
  if (t == 0){
    float a = bf3[0];
    for (int k = 0; k < 128; ++k) a += h2s[k] * Wf3[k];
    dout[r] = a;
  }
}

// ---------------- host ----------------
extern "C" void kernel_launch(void* const* d_in, const int* in_sizes, int n_in,
                              void* d_out, int out_size, void* d_ws, size_t ws_size,
                              hipStream_t stream){
  const float* x      = (const float*)d_in[0];
  const int*   ei     = (const int*)d_in[1];
  const float* W_uni  = (const float*)d_in[5];
  const float* b_uni  = (const float*)d_in[6];
  const float* W_gat  = (const float*)d_in[10];
  const float* att_s  = (const float*)d_in[11];
  const float* att_d  = (const float*)d_in[12];
  const float* b_gat  = (const float*)d_in[13];
  const float* g1     = (const float*)d_in[14];
  const float* be1    = (const float*)d_in[15];
  const float* g2     = (const float*)d_in[16];
  const float* be2    = (const float*)d_in[17];
  const float* g3     = (const float*)d_in[18];
  const float* be3    = (const float*)d_in[19];
  const float* W_in   = (const float*)d_in[20];
  const float* w_conv = (const float*)d_in[21];
  const float* b_conv = (const float*)d_in[22];
  const float* W_xp   = (const float*)d_in[23];
  const float* W_dt   = (const float*)d_in[24];
  const float* b_dt   = (const float*)d_in[25];
  const float* A_log  = (const float*)d_in[26];
  const float* D_p    = (const float*)d_in[27];
  const float* W_out  = (const float*)d_in[28];
  const float* W_m1   = (const float*)d_in[29];
  const float* b_m1   = (const float*)d_in[30];
  const float* W_m2   = (const float*)d_in[31];
  const float* b_m2   = (const float*)d_in[32];
  const float* Wf1    = (const float*)d_in[33];
  const float* bf1    = (const float*)d_in[34];
  const float* Wf2    = (const float*)d_in[35];
  const float* bf2    = (const float*)d_in[36];
  const float* Wf3    = (const float*)d_in[37];
  const float* bf3    = (const float*)d_in[38];
  float* dout = (float*)d_out;

  char* base = (char*)d_ws;
  size_t off = 0;
  auto alloc = [&](size_t b){ size_t r = off; off += (b + 255) & ~(size_t)255; return r; };

  size_t oR1    = alloc((size_t)NN*1024*2);   // Xb -> xzb -> out1 (33.5MB each, aliased)
  size_t oH0b   = alloc((size_t)NN*512*2);    // h0b bf16
  size_t oWuniT = alloc(512*1024*2);
  size_t oWgatT = alloc(512*512*2);
  size_t oWinT  = alloc(1024*512*2);
  size_t oWfusT = alloc(512*512*2);
  size_t oWbcT  = alloc(128*512*2);
  size_t oWoutT = alloc(512*512*2);
  size_t oWm1T  = alloc(1024*512*2);
  size_t oWm2T  = alloc(512*1024*2);
  size_t oBuni  = alloc(512*4);
  size_t oXh    = alloc((size_t)NN*512*2);    // xh bf16 -> yfb bf16
  size_t oAs    = alloc(NN*4);
  size_t oAd    = alloc(NN*4);
  size_t oCnt   = alloc(NN*4);
  size_t oCur   = alloc(NN*4);
  size_t oOff   = alloc((NN+1)*4);
  size_t oSrcs  = alloc((size_t)EE*4);
  size_t oAlph  = alloc((size_t)EE*4);
  size_t oGat   = alloc((size_t)NN*512*4);    // gat f32 -> mlp1b bf16
  size_t oXc    = alloc((size_t)NN*512*4);    // xc f32 -> out0 f32
  size_t oXcb   = alloc((size_t)NN*512*2);    // xcb bf16 -> Pc/Hc f32 (scan) -> out0b bf16
  size_t oDt    = alloc((size_t)NN*512*4);    // dt f32 -> h2raw f32
  size_t oBC    = alloc((size_t)NN*32*4);
  size_t oStats = alloc(6*512*4);             // s1,q1,s2,q2,s3,q3
  size_t oPool  = alloc(8*512*4);

  short* Xb   = (short*)(base + oR1);
  unsigned short* xzb = (unsigned short*)(base + oR1);
  float* out1 = (float*)(base + oR1);
  unsigned short* h0b = (unsigned short*)(base + oH0b);
  short* WuniT = (short*)(base + oWuniT);
  short* WgatT = (short*)(base + oWgatT);
  short* WinT  = (short*)(base + oWinT);
  short* WfusT = (short*)(base + oWfusT);
  short* WbcT  = (short*)(base + oWbcT);
  short* WoutT = (short*)(base + oWoutT);
  short* Wm1T  = (short*)(base + oWm1T);
  short* Wm2T  = (short*)(base + oWm2T);
  float* buniP = (float*)(base + oBuni);
  unsigned short* xh  = (unsigned short*)(base + oXh);
  unsigned short* yfb = (unsigned short*)(base + oXh);
  float* a_s = (float*)(base + oAs);
  float* a_d = (float*)(base + oAd);
  int* cnt = (int*)(base + oCnt);
  int* cur = (int*)(base + oCur);
  int* offs = (int*)(base + oOff);
  int* srcs = (int*)(base + oSrcs);
  float* alphas = (float*)(base + oAlph);
  float* gat = (float*)(base + oGat);
  unsigned short* mlp1b = (unsigned short*)(base + oGat);
  float* xc = (float*)(base + oXc);
  float* out0 = (float*)(base + oXc);
  unsigned short* xcb  = (unsigned short*)(base + oXcb);
  unsigned short* out0b = (unsigned short*)(base + oXcb);
  // scan scratch aliases the xcb region (dead between BC-GEMM and combine_out0):
  // Pc = 8*32*512*16 f32 = 8 MB, Hc same; total 16 MB <= 16.78 MB region.
  float* Pc = (float*)(base + oXcb);
  float* Hc = Pc + (size_t)8*NCK*512*16;
  float* dt = (float*)(base + oDt);
  float* h2raw = (float*)(base + oDt);
  float* BC = (float*)(base + oBC);
  float* s1 = (float*)(base + oStats);
  float* q1 = s1 + 512;
  float* s2 = q1 + 512;
  float* q2 = s2 + 512;
  float* s3 = q2 + 512;
  float* q3 = s3 + 512;
  float* poolsum = (float*)(base + oPool);

  // zero the accumulators
  hipMemsetAsync(cnt, 0, NN*4, stream);
  hipMemsetAsync(s1, 0, 6*512*4, stream);
  hipMemsetAsync(poolsum, 0, 8*512*4, stream);

  // prep: convert/transpose weights, convert x, fuse W_xp@W_dt
  transposeW<<<(512*1024+255)/256, 256, 0, stream>>>(W_uni, WuniT, 1024, 496, 512, 496, 0);
  transposeW<<<(512*512+255)/256, 256, 0, stream>>>(W_gat, WgatT, 512, 512, 512, 512, 0);
  transposeW<<<(1024*512+255)/256, 256, 0, stream>>>(W_in, WinT, 512, 1024, 1024, 1024, 0);
  transposeW<<<(128*512+255)/256, 256, 0, stream>>>(W_xp, WbcT, 512, 32, 128, 64, 32);
  transposeW<<<(512*512+255)/256, 256, 0, stream>>>(W_out, WoutT, 512, 512, 512, 512, 0);
  transposeW<<<(1024*512+255)/256, 256, 0, stream>>>(W_m1, Wm1T, 512, 1024, 1024, 1024, 0);
  transposeW<<<(512*1024+255)/256, 256, 0, stream>>>(W_m2, Wm2T, 1024, 512, 512, 512, 0);
  fuse_wdt<<<(512*512+255)/256, 256, 0, stream>>>(W_xp, W_dt, WfusT);
  pad_bias<<<2, 256, 0, stream>>>(b_uni, buniP);
  conv_x<<<(NN*1024+255)/256, 256, 0, stream>>>(x, Xb);

  dim3 g4(128, 4), g8(128, 8), g1b(128, 1);
  // h0 = [x@W_uni + b_uni | pe]
  gemm_bt<<<g4, 256, 0, stream>>>(Xb, WuniT, nullptr, h0b, buniP, nullptr, 1024, 512, 0);
  pe_fill<<<(NN+255)/256, 256, 0, stream>>>(x, h0b);
  // xh = h0 @ W_gat  (bf16)
  gemm_bt<<<g4, 256, 0, stream>>>((const short*)h0b, WgatT, nullptr, xh, nullptr, nullptr, 512, 512, 0);
  att_proj<<<NN/4, 256, 0, stream>>>(xh, att_s, att_d, a_s, a_d);
  // GAT
  gat_hist<<<EE/256, 256, 0, stream>>>(ei, cnt);
  gat_prefix<<<1, 256, 0, stream>>>(cnt, offs, cur);
  gat_scatter<<<EE/256, 256, 0, stream>>>(ei, a_s, a_d, cur, srcs, alphas);
  gat_agg<<<NN/4, 256, 0, stream>>>(offs, srcs, alphas, xh, a_s, a_d, b_gat, gat);
  colstats<<<128, 256, 0, stream>>>(gat, s1, q1);
  // Mamba path
  gemm_bt<<<g8, 256, 0, stream>>>((const short*)h0b, WinT, nullptr, xzb, nullptr, nullptr, 512, 1024, 0);
  {
    dim3 gc(NN, 2);
    conv_silu<<<gc, 256, 0, stream>>>(xzb, w_conv, b_conv, xc, xcb);
  }
  gemm_bt<<<g4, 256, 0, stream>>>((const short*)xcb, WfusT, dt, nullptr, b_dt, nullptr, 512, 512, 2);
  gemm_bt<<<g1b, 256, 0, stream>>>((const short*)xcb, WbcT, BC, nullptr, nullptr, nullptr, 512, 32, 0);
  // chunked parallel scan (xcb region is dead from here until combine_out0)
  {
    dim3 gs(8*NCK, 32);
    ssm_scan1<<<gs, 256, 0, stream>>>(dt, xc, BC, A_log, Pc, Hc);
    ssm_carry<<<256, 256, 0, stream>>>(Pc, Hc);
    ssm_scan2<<<gs, 256, 0, stream>>>(dt, xc, BC, xzb, A_log, D_p, Hc, yfb);
  }
  gemm_bt<<<g4, 256, 0, stream>>>((const short*)yfb, WoutT, h2raw, nullptr, nullptr, nullptr, 512, 512, 0);
  colstats<<<128, 256, 0, stream>>>(h2raw, s2, q2);
  // combine + MLP residual
  combine_out0<<<128, 256, 0, stream>>>(gat, h2raw, s1, q1, s2, q2, g1, be1, g2, be2, out0, out0b);
  gemm_bt<<<g8, 256, 0, stream>>>((const short*)out0b, Wm1T, nullptr, mlp1b, b_m1, nullptr, 512, 1024, 1);
  gemm_bt<<<g4, 256, 0, stream>>>((const short*)mlp1b, Wm2T, out1, nullptr, b_m2, out0, 1024, 512, 0);
  colstats<<<128, 256, 0, stream>>>(out1, s3, q3);
  out2_pool<<<128, 256, 0, stream>>>(out1, s3, q3, g3, be3, poolsum);
  head<<<8, 256, 0, stream>>>(poolsum, Wf1, bf1, Wf2, bf2, Wf3, bf3, dout);
}

// Round 8
// 915.185 us; speedup vs baseline: 2.6522x; 1.2205x over previous
//
#include <hip/hip_runtime.h>
#include <math.h>

#define NN 16384
#define CD 512
#define EE 262144
#define LL 2048
#define NCK 32   // time chunks per batch
#define TC 64    // steps per chunk

typedef __attribute__((ext_vector_type(8))) short short8;
typedef __attribute__((ext_vector_type(4))) float floatx4;

__device__ __forceinline__ unsigned short f2b(float f){
  unsigned int u = __float_as_uint(f);
  unsigned int r = (u + 0x7fffu + ((u>>16)&1u)) >> 16;
  return (unsigned short)r;
}
__device__ __forceinline__ float b2f(unsigned short h){
  return __uint_as_float(((unsigned int)h)<<16);
}

// ---------------- prep kernels ----------------

// W: K x Nsub (row pitch `pitch`, col offset col0) -> Bt: Npad x K bf16 (zero-padded rows)
__global__ void transposeW(const float* __restrict__ W, short* __restrict__ Bt,
                           int K, int Nsub, int Npad, int pitch, int col0){
  int idx = blockIdx.x*256 + threadIdx.x;
  if (idx >= Npad*K) return;
  int n = idx / K, k = idx - n*K;
  float v = (n < Nsub) ? W[(size_t)k*pitch + col0 + n] : 0.f;
  Bt[idx] = (short)f2b(v);
}

// Wfused^T[j][i] = sum_r W_xp[i,r]*W_dt[r,j]  (512x512 bf16, Bt layout)
__global__ void fuse_wdt(const float* __restrict__ W_xp, const float* __restrict__ W_dt,
                         short* __restrict__ Wft){
  int idx = blockIdx.x*256 + threadIdx.x;   // 512*512
  if (idx >= 512*512) return;
  int i = idx & 511;      // input channel (k-dim)
  int j = idx >> 9;       // output channel
  float a = 0.f;
  #pragma unroll 8
  for (int r = 0; r < 32; ++r) a += W_xp[(size_t)i*64 + r] * W_dt[(size_t)r*512 + j];
  Wft[idx] = (short)f2b(a);
}

__global__ void pad_bias(const float* __restrict__ b, float* __restrict__ out){
  int i = blockIdx.x*256 + threadIdx.x;
  if (i < 512) out[i] = (i < 496) ? b[i] : 0.f;
}

// x (16384 x 1026) cols 2..1025 -> Xb bf16 (16384 x 1024)
__global__ void conv_x(const float* __restrict__ x, short* __restrict__ Xb){
  int idx = blockIdx.x*256 + threadIdx.x;
  if (idx >= NN*1024) return;
  int r = idx >> 10, c = idx & 1023;
  Xb[idx] = (short)f2b(x[(size_t)r*1026 + 2 + c]);
}

// positional encodings into h0b cols 496..511
__global__ void pe_fill(const float* __restrict__ x, unsigned short* __restrict__ h0b){
  int r = blockIdx.x*256 + threadIdx.x;
  if (r >= NN) return;
  float p0 = x[(size_t)r*1026 + 0], p1 = x[(size_t)r*1026 + 1];
  const float dn[4] = {1.f, 10.f, 100.f, 1000.f};
  unsigned short* o = h0b + (size_t)r*512 + 496;
  #pragma unroll
  for (int q = 0; q < 4; ++q){
    o[2*q]     = f2b(sinf(p0/dn[q]));
    o[2*q+1]   = f2b(cosf(p0/dn[q]));
    o[8+2*q]   = f2b(sinf(p1/dn[q]));
    o[8+2*q+1] = f2b(cosf(p1/dn[q]));
  }
}

// ---------------- GEMM (A MxK bf16 row-major, Bt NpadxK bf16 row-major) ----------------
// 128x128 tile, 4 waves (2x2), each wave 64x64 via 4x4 mfma_f32_16x16x32_bf16 frags.
// Staging via global_load_lds width=16 (m97 pattern): wave w stages rows
// [w*32, w*32+32) of As and Bs; LDS dest is wave-uniform base + lane*16B which
// linearly matches the row-major [128][32] tile (lane l -> row +(l>>2), col (l&3)*8).
#define GLDS(g, l) __builtin_amdgcn_global_load_lds((const __attribute__((address_space(1))) void*)(g), (__attribute__((address_space(3))) void*)(l), 16, 0, 0)

__global__ __launch_bounds__(256)
void gemm_bt(const short* __restrict__ A, const short* __restrict__ Bt,
             float* __restrict__ Cf, unsigned short* __restrict__ Cb,
             const float* __restrict__ bias, const float* __restrict__ resid,
             int K, int Nvalid, int epi){
  __shared__ __align__(16) short As[128*32];
  __shared__ __align__(16) short Bs[128*32];
  int tid = threadIdx.x;
  int m0 = blockIdx.x * 128;
  int n0 = blockIdx.y * 128;
  int lane = tid & 63, wave = tid >> 6;
  int wm = wave >> 1, wn = wave & 1;
  int lr = lane & 15, lk = lane >> 4;

  floatx4 acc[4][4];
  #pragma unroll
  for (int m = 0; m < 4; ++m)
    #pragma unroll
    for (int n = 0; n < 4; ++n) acc[m][n] = (floatx4)0.f;

  int wrow = wave * 32;          // wave's 32-row stripe of the tile
  int srow = lane >> 2;          // 0..15
  int scol = (lane & 3) * 8;     // 0,8,16,24 (elements)

  const short* gA0 = A  + (size_t)(m0 + wrow + srow)*K      + scol;
  const short* gA1 = A  + (size_t)(m0 + wrow + 16 + srow)*K + scol;
  const short* gB0 = Bt + (size_t)(n0 + wrow + srow)*K      + scol;
  const short* gB1 = Bt + (size_t)(n0 + wrow + 16 + srow)*K + scol;

  for (int k0 = 0; k0 < K; k0 += 32){
    __syncthreads();
    GLDS(gA0 + k0, &As[wrow*32]);
    GLDS(gA1 + k0, &As[(wrow+16)*32]);
    GLDS(gB0 + k0, &Bs[wrow*32]);
    GLDS(gB1 + k0, &Bs[(wrow+16)*32]);
    __syncthreads();
    short8 af[4], bf[4];
    #pragma unroll
    for (int m = 0; m < 4; ++m) af[m] = *(const short8*)&As[(wm*64 + m*16 + lr)*32 + lk*8];
    #pragma unroll
    for (int n = 0; n < 4; ++n) bf[n] = *(const short8*)&Bs[(wn*64 + n*16 + lr)*32 + lk*8];
    #pragma unroll
    for (int m = 0; m < 4; ++m)
      #pragma unroll
      for (int n = 0; n < 4; ++n)
        acc[m][n] = __builtin_amdgcn_mfma_f32_16x16x32_bf16(af[m], bf[n], acc[m][n], 0, 0, 0);
  }

  #pragma unroll
  for (int m = 0; m < 4; ++m){
    #pragma unroll
    for (int n = 0; n < 4; ++n){
      int col = n0 + wn*64 + n*16 + lr;
      if (col < Nvalid){
        #pragma unroll
        for (int r = 0; r < 4; ++r){
          int row = m0 + wm*64 + m*16 + lk*4 + r;
          float v = acc[m][n][r];
          if (bias)  v += bias[col];
          if (resid) v += resid[(size_t)row*Nvalid + col];
          if (epi == 1) v = fmaxf(v, 0.f);
          else if (epi == 2) v = (v > 20.f) ? v : log1pf(expf(v));
          size_t o = (size_t)row*Nvalid + col;
          if (Cf) Cf[o] = v;
          if (Cb) Cb[o] = f2b(v);
        }
      }
    }
  }
}

// ---------------- attention scalars ----------------
__global__ void att_proj(const unsigned short* __restrict__ xh,
                         const float* __restrict__ att_src, const float* __restrict__ att_dst,
                         float* __restrict__ a_s, float* __restrict__ a_d){
  int wave = threadIdx.x >> 6, lane = threadIdx.x & 63;
  int r = blockIdx.x*4 + wave;
  const unsigned short* xr = xh + (size_t)r*512;
  float ps = 0.f, pd = 0.f;
  #pragma unroll
  for (int j = 0; j < 8; ++j){
    float v = b2f(xr[lane + 64*j]);
    ps += v * att_src[lane + 64*j];
    pd += v * att_dst[lane + 64*j];
  }
  #pragma unroll
  for (int m = 32; m >= 1; m >>= 1){ ps += __shfl_xor(ps, m); pd += __shfl_xor(pd, m); }
  if (lane == 0){ a_s[r] = ps; a_d[r] = pd; }
}

// ---------------- GAT bucketing ----------------
__global__ void gat_hist(const int* __restrict__ ei, int* __restrict__ cnt){
  int e = blockIdx.x*256 + threadIdx.x;
  if (e < EE) atomicAdd(&cnt[ei[EE + e]], 1);
}

__global__ void gat_prefix(const int* __restrict__ cnt, int* __restrict__ offsets, int* __restrict__ cursor){
  __shared__ int part[256];
  int t = threadIdx.x;
  int s = 0;
  for (int i = 0; i < 64; ++i) s += cnt[t*64 + i];
  part[t] = s;
  __syncthreads();
  for (int off = 1; off < 256; off <<= 1){
    int v = (t >= off) ? part[t - off] : 0;
    __syncthreads();
    part[t] += v;
    __syncthreads();
  }
  int run = part[t] - s;   // exclusive base
  for (int i = 0; i < 64; ++i){
    int c = cnt[t*64 + i];
    offsets[t*64 + i] = run;
    cursor[t*64 + i]  = run;
    run += c;
  }
  if (t == 255) offsets[NN] = run;
}

__global__ void gat_scatter(const int* __restrict__ ei, const float* __restrict__ a_s,
                            const float* __restrict__ a_d, int* __restrict__ cursor,
                            int* __restrict__ srcs, float* __restrict__ alphas){
  int e = blockIdx.x*256 + threadIdx.x;
  if (e >= EE) return;
  int sN = ei[e], dN = ei[EE + e];
  int p = atomicAdd(&cursor[dN], 1);
  srcs[p] = sN;
  float al = a_s[sN] + a_d[dN];
  alphas[p] = (al > 0.f) ? al : 0.2f*al;
}

// one wave per dst node: softmax over in-edges (+self loop), gather-weighted sum
__global__ __launch_bounds__(256)
void gat_agg(const int* __restrict__ offsets, const int* __restrict__ srcs,
             const float* __restrict__ alphas, const unsigned short* __restrict__ xh,
             const float* __restrict__ a_s, const float* __restrict__ a_d,
             const float* __restrict__ b_gat, float* __restrict__ gat){
  int wave = threadIdx.x >> 6, lane = threadIdx.x & 63;
  int i = blockIdx.x*4 + wave;
  int beg = offsets[i], end = offsets[i+1];
  float asd = a_s[i] + a_d[i];
  float al0 = (asd > 0.f) ? asd : 0.2f*asd;
  float mx = al0;
  for (int p = beg + lane; p < end; p += 64) mx = fmaxf(mx, alphas[p]);
  #pragma unroll
  for (int m = 32; m >= 1; m >>= 1) mx = fmaxf(mx, __shfl_xor(mx, m));
  float se = 0.f;
  for (int p = beg + lane; p < end; p += 64) se += __expf(alphas[p] - mx);
  #pragma unroll
  for (int m = 32; m >= 1; m >>= 1) se += __shfl_xor(se, m);
  float den = se + __expf(al0 - mx);
  float inv = 1.f/(den + 1e-16f);
  float acc[8] = {0,0,0,0,0,0,0,0};
  for (int p = beg; p < end; ++p){
    float w = __expf(alphas[p] - mx) * inv;
    const unsigned short* xr = xh + (size_t)srcs[p]*512;
    #pragma unroll
    for (int j = 0; j < 8; ++j) acc[j] += w * b2f(xr[lane + 64*j]);
  }
  {
    float w0 = __expf(al0 - mx) * inv;
    const unsigned short* xr = xh + (size_t)i*512;
    #pragma unroll
    for (int j = 0; j < 8; ++j) acc[j] += w0 * b2f(xr[lane + 64*j]);
  }
  #pragma unroll
  for (int j = 0; j < 8; ++j)
    gat[(size_t)i*512 + lane + 64*j] = acc[j] + b_gat[lane + 64*j];
}

// ---------------- conv + silu ----------------
__global__ void conv_silu(const unsigned short* __restrict__ xzb,
                          const float* __restrict__ w_conv, const float* __restrict__ b_conv,
                          float* __restrict__ xc, unsigned short* __restrict__ xcb){
  int r = blockIdx.x;
  int c = blockIdx.y*256 + threadIdx.x;
  int t = r & (LL - 1);
  float acc = b_conv[c];
  #pragma unroll
  for (int k = 0; k < 4; ++k){
    int tt = t + k - 3;
    if (tt >= 0) acc += b2f(xzb[(size_t)(r + k - 3)*1024 + c]) * w_conv[c*4 + k];
  }
  float s = acc / (1.f + __expf(-acc));
  xc[(size_t)r*512 + c] = s;
  xcb[(size_t)r*512 + c] = f2b(s);
}

// ---------------- SSM chunked parallel scan (s in registers) ----------------
// Thread per (b, chunk, d); all 16 state dims in VGPRs. Layout [bc][d][s].
__global__ __launch_bounds__(256)
void ssm_scan1(const float* __restrict__ dt, const float* __restrict__ xc,
               const float* __restrict__ BC, const float* __restrict__ A_log,
               float* __restrict__ Pc, float* __restrict__ Hc){
  int d  = blockIdx.y*256 + threadIdx.x;   // 0..511
  int bc = blockIdx.x;                     // b*NCK + ck
  int b  = bc >> 5;
  int ck = bc & (NCK - 1);
  float A[16], h[16];
  #pragma unroll
  for (int s = 0; s < 16; ++s){ A[s] = -__expf(A_log[d*16 + s]); h[s] = 0.f; }
  float sdt = 0.f;
  size_t r = (size_t)b*LL + (size_t)ck*TC;
  for (int t = 0; t < TC; ++t, ++r){
    float dtv = dt[r*512 + d];
    float xv  = xc[r*512 + d];
    float dx  = dtv * xv;
    const floatx4* bp = (const floatx4*)&BC[r*32];
    float Bf[16];
    *(floatx4*)&Bf[0]  = bp[0];
    *(floatx4*)&Bf[4]  = bp[1];
    *(floatx4*)&Bf[8]  = bp[2];
    *(floatx4*)&Bf[12] = bp[3];
    #pragma unroll
    for (int s = 0; s < 16; ++s){
      float a = __expf(dtv * A[s]);
      h[s] = h[s]*a + dx*Bf[s];
    }
    sdt += dtv;
  }
  size_t idx = ((size_t)bc*512 + d)*16;
  float P[16];
  #pragma unroll
  for (int s = 0; s < 16; ++s) P[s] = __expf(A[s]*sdt);   // prod(a) = exp(A*sum dt)
  #pragma unroll
  for (int q = 0; q < 4; ++q){
    *(floatx4*)&Pc[idx + q*4] = *(floatx4*)&P[q*4];
    *(floatx4*)&Hc[idx + q*4] = *(floatx4*)&h[q*4];
  }
}

// Carry pass: one thread per (b,d,s) stripe; sequential over 32 chunks.
// In-place: Hc[c] is overwritten with the chunk's INPUT carry.
__global__ void ssm_carry(const float* __restrict__ Pc, float* __restrict__ Hc){
  int gid = blockIdx.x*256 + threadIdx.x;   // 0..65535
  int b  = gid >> 13;                       // 512*16 = 8192 stripes per batch
  int ds = gid & 8191;
  size_t idx = ((size_t)b*NCK)*8192 + ds;
  float carry = 0.f;
  for (int c = 0; c < NCK; ++c){
    float P = Pc[idx], H = Hc[idx];
    Hc[idx] = carry;
    carry = H + P*carry;
    idx += 8192;
  }
}

// Pass 2: re-scan each chunk from its true carry-in; emit gated output.
__global__ __launch_bounds__(256)
void ssm_scan2(const float* __restrict__ dt, const float* __restrict__ xc,
               const float* __restrict__ BC, const unsigned short* __restrict__ xzb,
               const float* __restrict__ A_log, const float* __restrict__ D_p,
               const float* __restrict__ Cin, unsigned short* __restrict__ yfb){
  int d  = blockIdx.y*256 + threadIdx.x;
  int bc = blockIdx.x;
  int b  = bc >> 5;
  int ck = bc & (NCK - 1);
  float A[16], h[16];
  size_t idx = ((size_t)bc*512 + d)*16;
  #pragma unroll
  for (int s = 0; s < 16; ++s){ A[s] = -__expf(A_log[d*16 + s]); h[s] = Cin[idx + s]; }
  float Dp = D_p[d];
  size_t r = (size_t)b*LL + (size_t)ck*TC;
  for (int t = 0; t < TC; ++t, ++r){
    float dtv = dt[r*512 + d];
    float xv  = xc[r*512 + d];
    float dx  = dtv * xv;
    const floatx4* bp = (const floatx4*)&BC[r*32];
    float Bf[16], Cf[16];
    *(floatx4*)&Bf[0]  = bp[0];
    *(floatx4*)&Bf[4]  = bp[1];
    *(floatx4*)&Bf[8]  = bp[2];
    *(floatx4*)&Bf[12] = bp[3];
    *(floatx4*)&Cf[0]  = bp[4];
    *(floatx4*)&Cf[4]  = bp[5];
    *(floatx4*)&Cf[8]  = bp[6];
    *(floatx4*)&Cf[12] = bp[7];
    float y = 0.f;
    #pragma unroll
    for (int s = 0; s < 16; ++s){
      float a = __expf(dtv * A[s]);
      h[s] = h[s]*a + dx*Bf[s];
      y += h[s]*Cf[s];
    }
    float z  = b2f(xzb[r*1024 + 512 + d]);
    float sz = z / (1.f + __expf(-z));
    yfb[r*512 + d] = f2b((y + Dp*xv) * sz);
  }
}

// ---------------- column stats (sum, sumsq) ----------------
__global__ void colstats(const float* __restrict__ X, float* __restrict__ sums, float* __restrict__ sqs){
  int c0 = threadIdx.x;
  int row0 = blockIdx.x * 128;
  float s0=0,q0=0,s1=0,q1=0;
  for (int i = 0; i < 128; ++i){
    const float* rp = X + (size_t)(row0+i)*512;
    float a = rp[c0], b = rp[c0+256];
    s0 += a; q0 += a*a; s1 += b; q1 += b*b;
  }
  atomicAdd(&sums[c0], s0);      atomicAdd(&sqs[c0], q0);
  atomicAdd(&sums[c0+256], s1);  atomicAdd(&sqs[c0+256], q1);
}

// out0 = BN(gat)*g1+be1 + BN(h2)*g2+be2  (f32 + bf16)
__global__ void combine_out0(const float* __restrict__ gat, const float* __restrict__ h2,
                             const float* __restrict__ s1, const float* __restrict__ q1,
                             const float* __restrict__ s2, const float* __restrict__ q2,
                             const float* __restrict__ g1, const float* __restrict__ be1,
                             const float* __restrict__ g2, const float* __restrict__ be2,
                             float* __restrict__ out0, unsigned short* __restrict__ out0b){
  int t = threadIdx.x;
  int row0 = blockIdx.x * 128;
  const float invN = 1.f/16384.f;
  float sc1[2], sc2[2], off[2];
  #pragma unroll
  for (int h = 0; h < 2; ++h){
    int c = t + h*256;
    float m1 = s1[c]*invN, v1 = q1[c]*invN - m1*m1;
    float m2 = s2[c]*invN, v2 = q2[c]*invN - m2*m2;
    float a1 = rsqrtf(v1 + 1e-5f) * g1[c];
    float a2 = rsqrtf(v2 + 1e-5f) * g2[c];
    sc1[h] = a1; sc2[h] = a2;
    off[h] = be1[c] + be2[c] - m1*a1 - m2*a2;
  }
  for (int i = 0; i < 128; ++i){
    size_t ro = (size_t)(row0+i)*512;
    #pragma unroll
    for (int h = 0; h < 2; ++h){
      int c = t + h*256;
      float v = gat[ro+c]*sc1[h] + h2[ro+c]*sc2[h] + off[h];
      out0[ro+c] = v;
      out0b[ro+c] = f2b(v);
    }
  }
}

// out2 = relu(BN(out1)*g3+be3); per-batch column sums -> poolsum
__global__ void out2_pool(const float* __restrict__ out1,
                          const float* __restrict__ s3, const float* __restrict__ q3,
                          const float* __restrict__ g3, const float* __restrict__ be3,
                          float* __restrict__ poolsum){
  int t = threadIdx.x;
  int row0 = blockIdx.x * 128;
  int bidx = row0 / LL;
  const float invN = 1.f/16384.f;
  float sc[2], off[2], acc[2] = {0.f, 0.f};
  #pragma unroll
  for (int h = 0; h < 2; ++h){
    int c = t + h*256;
    float m = s3[c]*invN, v = q3[c]*invN - m*m;
    float a = rsqrtf(v + 1e-5f) * g3[c];
    sc[h] = a; off[h] = be3[c] - m*a;
  }
  for (int i = 0; i < 128; ++i){
    size_t ro = (size_t)(row0+i)*512;
    #pragma unroll
    for (int h = 0; h < 2; ++h){
      int c = t + h*256;
      float v = fmaxf(out1[ro+c]*sc[h] + off[h], 0.f);
      acc[h] += v;
    }
  }
  atomicAdd(&poolsum[bidx*512 + t], acc[0]);
  atomicAdd(&poolsum[bidx*512 + t + 256], acc[1]);
}

// final head MLP: one block per batch row
__global__ __launch_bounds__(256)
void head(const float* __restrict__ poolsum,
          const float* __restrict__ Wf1, const float* __restrict__ bf1,
          const float* __restrict__ Wf2, const float* __restrict__ bf2,
          const float* __restrict__ Wf3, const float* __restrict__ bf3,
          float* __restrict__ dout){
  int r = blockIdx.x, t = threadIdx.x;
  __shared__ float pool[512];
  __shared__ float h1s[256];
  __shared__ float h2s[128];
  for (int i = t; i < 512; i += 256){
    float v = poolsum[r*512 + i] * (1.f/2048.f);
    pool[i] = v;
    dout[8 + r*512 + i] = v;
  }
  __syncthreads();
  {
    float a = bf1[t];
    for (int k = 0; k < 512; ++k) a += pool[k] * Wf1[(size_t)k*256 + t];
    h1s[t] = fmaxf(a, 0.f);
  }
  __syncthreads();
  if (t < 128){
    float a = bf2[t];
    for (int k = 0; k < 256; ++k) a += h1s[k] * Wf2[(size_t)k*128 + t];
    h2s[t] = fmaxf(a, 0.f);
  }
  __syncthreads();
  if (t == 0){
    float a = bf3[0];
    for (int k = 0; k < 128; ++k) a += h2s[k] * Wf3[k];
    dout[r] = a;
  }
}

// ---------------- host ----------------
extern "C" void kernel_launch(void* const* d_in, const int* in_sizes, int n_in,
                              void* d_out, int out_size, void* d_ws, size_t ws_size,
                              hipStream_t stream){
  const float* x      = (const float*)d_in[0];
  const int*   ei     = (const int*)d_in[1];
  const float* W_uni  = (const float*)d_in[5];
  const float* b_uni  = (const float*)d_in[6];
  const float* W_gat  = (const float*)d_in[10];
  const float* att_s  = (const float*)d_in[11];
  const float* att_d  = (const float*)d_in[12];
  const float* b_gat  = (const float*)d_in[13];
  const float* g1     = (const float*)d_in[14];
  const float* be1    = (const float*)d_in[15];
  const float* g2     = (const float*)d_in[16];
  const float* be2    = (const float*)d_in[17];
  const float* g3     = (const float*)d_in[18];
  const float* be3    = (const float*)d_in[19];
  const float* W_in   = (const float*)d_in[20];
  const float* w_conv = (const float*)d_in[21];
  const float* b_conv = (const float*)d_in[22];
  const float* W_xp   = (const float*)d_in[23];
  const float* W_dt   = (const float*)d_in[24];
  const float* b_dt   = (const float*)d_in[25];
  const float* A_log  = (const float*)d_in[26];
  const float* D_p    = (const float*)d_in[27];
  const float* W_out  = (const float*)d_in[28];
  const float* W_m1   = (const float*)d_in[29];
  const float* b_m1   = (const float*)d_in[30];
  const float* W_m2   = (const float*)d_in[31];
  const float* b_m2   = (const float*)d_in[32];
  const float* Wf1    = (const float*)d_in[33];
  const float* bf1    = (const float*)d_in[34];
  const float* Wf2    = (const float*)d_in[35];
  const float* bf2    = (const float*)d_in[36];
  const float* Wf3    = (const float*)d_in[37];
  const float* bf3    = (const float*)d_in[38];
  float* dout = (float*)d_out;

  char* base = (char*)d_ws;
  size_t off = 0;
  auto alloc = [&](size_t b){ size_t r = off; off += (b + 255) & ~(size_t)255; return r; };

  size_t oR1    = alloc((size_t)NN*1024*2);   // Xb -> xzb -> out1 (33.5MB each, aliased)
  size_t oH0b   = alloc((size_t)NN*512*2);    // h0b bf16
  size_t oWuniT = alloc(512*1024*2);
  size_t oWgatT = alloc(512*512*2);
  size_t oWinT  = alloc(1024*512*2);
  size_t oWfusT = alloc(512*512*2);
  size_t oWbcT  = alloc(128*512*2);
  size_t oWoutT = alloc(512*512*2);
  size_t oWm1T  = alloc(1024*512*2);
  size_t oWm2T  = alloc(512*1024*2);
  size_t oBuni  = alloc(512*4);
  size_t oXh    = alloc((size_t)NN*512*2);    // xh bf16 -> yfb bf16
  size_t oAs    = alloc(NN*4);
  size_t oAd    = alloc(NN*4);
  size_t oCnt   = alloc(NN*4);
  size_t oCur   = alloc(NN*4);
  size_t oOff   = alloc((NN+1)*4);
  size_t oSrcs  = alloc((size_t)EE*4);
  size_t oAlph  = alloc((size_t)EE*4);
  size_t oGat   = alloc((size_t)NN*512*4);    // gat f32 -> mlp1b bf16
  size_t oXc    = alloc((size_t)NN*512*4);    // xc f32 -> out0 f32
  size_t oXcb   = alloc((size_t)NN*512*2);    // xcb bf16 -> Pc/Hc f32 (scan) -> out0b bf16
  size_t oDt    = alloc((size_t)NN*512*4);    // dt f32 -> h2raw f32
  size_t oBC    = alloc((size_t)NN*32*4);
  size_t oStats = alloc(6*512*4);             // s1,q1,s2,q2,s3,q3
  size_t oPool  = alloc(8*512*4);

  short* Xb   = (short*)(base + oR1);
  unsigned short* xzb = (unsigned short*)(base + oR1);
  float* out1 = (float*)(base + oR1);
  unsigned short* h0b = (unsigned short*)(base + oH0b);
  short* WuniT = (short*)(base + oWuniT);
  short* WgatT = (short*)(base + oWgatT);
  short* WinT  = (short*)(base + oWinT);
  short* WfusT = (short*)(base + oWfusT);
  short* WbcT  = (short*)(base + oWbcT);
  short* WoutT = (short*)(base + oWoutT);
  short* Wm1T  = (short*)(base + oWm1T);
  short* Wm2T  = (short*)(base + oWm2T);
  float* buniP = (float*)(base + oBuni);
  unsigned short* xh  = (unsigned short*)(base + oXh);
  unsigned short* yfb = (unsigned short*)(base + oXh);
  float* a_s = (float*)(base + oAs);
  float* a_d = (float*)(base + oAd);
  int* cnt = (int*)(base + oCnt);
  int* cur = (int*)(base + oCur);
  int* offs = (int*)(base + oOff);
  int* srcs = (int*)(base + oSrcs);
  float* alphas = (float*)(base + oAlph);
  float* gat = (float*)(base + oGat);
  unsigned short* mlp1b = (unsigned short*)(base + oGat);
  float* xc = (float*)(base + oXc);
  float* out0 = (float*)(base + oXc);
  unsigned short* xcb  = (unsigned short*)(base + oXcb);
  unsigned short* out0b = (unsigned short*)(base + oXcb);
  // scan scratch aliases the xcb region (dead between BC-GEMM and combine_out0):
  // Pc = 8*32*512*16 f32 = 8 MB, Hc same; total 16 MB <= 16.78 MB region.
  float* Pc = (float*)(base + oXcb);
  float* Hc = Pc + (size_t)8*NCK*512*16;
  float* dt = (float*)(base + oDt);
  float* h2raw = (float*)(base + oDt);
  float* BC = (float*)(base + oBC);
  float* s1 = (float*)(base + oStats);
  float* q1 = s1 + 512;
  float* s2 = q1 + 512;
  float* q2 = s2 + 512;
  float* s3 = q2 + 512;
  float* q3 = s3 + 512;
  float* poolsum = (float*)(base + oPool);

  // zero the accumulators
  hipMemsetAsync(cnt, 0, NN*4, stream);
  hipMemsetAsync(s1, 0, 6*512*4, stream);
  hipMemsetAsync(poolsum, 0, 8*512*4, stream);

  // prep: convert/transpose weights, convert x, fuse W_xp@W_dt
  transposeW<<<(512*1024+255)/256, 256, 0, stream>>>(W_uni, WuniT, 1024, 496, 512, 496, 0);
  transposeW<<<(512*512+255)/256, 256, 0, stream>>>(W_gat, WgatT, 512, 512, 512, 512, 0);
  transposeW<<<(1024*512+255)/256, 256, 0, stream>>>(W_in, WinT, 512, 1024, 1024, 1024, 0);
  transposeW<<<(128*512+255)/256, 256, 0, stream>>>(W_xp, WbcT, 512, 32, 128, 64, 32);
  transposeW<<<(512*512+255)/256, 256, 0, stream>>>(W_out, WoutT, 512, 512, 512, 512, 0);
  transposeW<<<(1024*512+255)/256, 256, 0, stream>>>(W_m1, Wm1T, 512, 1024, 1024, 1024, 0);
  transposeW<<<(512*1024+255)/256, 256, 0, stream>>>(W_m2, Wm2T, 1024, 512, 512, 512, 0);
  fuse_wdt<<<(512*512+255)/256, 256, 0, stream>>>(W_xp, W_dt, WfusT);
  pad_bias<<<2, 256, 0, stream>>>(b_uni, buniP);
  conv_x<<<(NN*1024+255)/256, 256, 0, stream>>>(x, Xb);

  dim3 g4(128, 4), g8(128, 8), g1b(128, 1);
  // h0 = [x@W_uni + b_uni | pe]
  gemm_bt<<<g4, 256, 0, stream>>>(Xb, WuniT, nullptr, h0b, buniP, nullptr, 1024, 512, 0);
  pe_fill<<<(NN+255)/256, 256, 0, stream>>>(x, h0b);
  // xh = h0 @ W_gat  (bf16)
  gemm_bt<<<g4, 256, 0, stream>>>((const short*)h0b, WgatT, nullptr, xh, nullptr, nullptr, 512, 512, 0);
  att_proj<<<NN/4, 256, 0, stream>>>(xh, att_s, att_d, a_s, a_d);
  // GAT
  gat_hist<<<EE/256, 256, 0, stream>>>(ei, cnt);
  gat_prefix<<<1, 256, 0, stream>>>(cnt, offs, cur);
  gat_scatter<<<EE/256, 256, 0, stream>>>(ei, a_s, a_d, cur, srcs, alphas);
  gat_agg<<<NN/4, 256, 0, stream>>>(offs, srcs, alphas, xh, a_s, a_d, b_gat, gat);
  colstats<<<128, 256, 0, stream>>>(gat, s1, q1);
  // Mamba path
  gemm_bt<<<g8, 256, 0, stream>>>((const short*)h0b, WinT, nullptr, xzb, nullptr, nullptr, 512, 1024, 0);
  {
    dim3 gc(NN, 2);
    conv_silu<<<gc, 256, 0, stream>>>(xzb, w_conv, b_conv, xc, xcb);
  }
  gemm_bt<<<g4, 256, 0, stream>>>((const short*)xcb, WfusT, dt, nullptr, b_dt, nullptr, 512, 512, 2);
  gemm_bt<<<g1b, 256, 0, stream>>>((const short*)xcb, WbcT, BC, nullptr, nullptr, nullptr, 512, 32, 0);
  // chunked parallel scan (xcb region is dead from here until combine_out0)
  {
    dim3 gs(8*NCK, 2);
    ssm_scan1<<<gs, 256, 0, stream>>>(dt, xc, BC, A_log, Pc, Hc);
    ssm_carry<<<256, 256, 0, stream>>>(Pc, Hc);
    ssm_scan2<<<gs, 256, 0, stream>>>(dt, xc, BC, xzb, A_log, D_p, Hc, yfb);
  }
  gemm_bt<<<g4, 256, 0, stream>>>((const short*)yfb, WoutT, h2raw, nullptr, nullptr, nullptr, 512, 512, 0);
  colstats<<<128, 256, 0, stream>>>(h2raw, s2, q2);
  // combine + MLP residual
  combine_out0<<<128, 256, 0, stream>>>(gat, h2raw, s1, q1, s2, q2, g1, be1, g2, be2, out0, out0b);
  gemm_bt<<<g8, 256, 0, stream>>>((const short*)out0b, Wm1T, nullptr, mlp1b, b_m1, nullptr, 512, 1024, 1);
  gemm_bt<<<g4, 256, 0, stream>>>((const short*)mlp1b, Wm2T, out1, nullptr, b_m2, out0, 1024, 512, 0);
  colstats<<<128, 256, 0, stream>>>(out1, s3, q3);
  out2_pool<<<128, 256, 0, stream>>>(out1, s3, q3, g3, be3, poolsum);
  head<<<8, 256, 0, stream>>>(poolsum, Wf1, bf1, Wf2, bf2, Wf3, bf3, dout);
}

// Round 10
// 909.175 us; speedup vs baseline: 2.6697x; 1.0066x over previous
//
#include <hip/hip_runtime.h>
#include <math.h>

#define NN 16384
#define CD 512
#define EE 262144
#define LL 2048
#define NCK 32   // time chunks per batch
#define TC 64    // steps per chunk

typedef __attribute__((ext_vector_type(8))) short short8;
typedef __attribute__((ext_vector_type(4))) float floatx4;

__device__ __forceinline__ unsigned short f2b(float f){
  unsigned int u = __float_as_uint(f);
  unsigned int r = (u + 0x7fffu + ((u>>16)&1u)) >> 16;
  return (unsigned short)r;
}
__device__ __forceinline__ float b2f(unsigned short h){
  return __uint_as_float(((unsigned int)h)<<16);
}

// ---------------- prep kernels ----------------

// W: K x Nsub (row pitch `pitch`, col offset col0) -> Bt: Npad x K bf16 (zero-padded rows)
__global__ void transposeW(const float* __restrict__ W, short* __restrict__ Bt,
                           int K, int Nsub, int Npad, int pitch, int col0){
  int idx = blockIdx.x*256 + threadIdx.x;
  if (idx >= Npad*K) return;
  int n = idx / K, k = idx - n*K;
  float v = (n < Nsub) ? W[(size_t)k*pitch + col0 + n] : 0.f;
  Bt[idx] = (short)f2b(v);
}

// Wfused^T[j][i] = sum_r W_xp[i,r]*W_dt[r,j]  (512x512 bf16, Bt layout)
__global__ void fuse_wdt(const float* __restrict__ W_xp, const float* __restrict__ W_dt,
                         short* __restrict__ Wft){
  int idx = blockIdx.x*256 + threadIdx.x;   // 512*512
  if (idx >= 512*512) return;
  int i = idx & 511;      // input channel (k-dim)
  int j = idx >> 9;       // output channel
  float a = 0.f;
  #pragma unroll 8
  for (int r = 0; r < 32; ++r) a += W_xp[(size_t)i*64 + r] * W_dt[(size_t)r*512 + j];
  Wft[idx] = (short)f2b(a);
}

__global__ void pad_bias(const float* __restrict__ b, float* __restrict__ out){
  int i = blockIdx.x*256 + threadIdx.x;
  if (i < 512) out[i] = (i < 496) ? b[i] : 0.f;
}

// x (16384 x 1026) cols 2..1025 -> Xb bf16 (16384 x 1024)
__global__ void conv_x(const float* __restrict__ x, short* __restrict__ Xb){
  int idx = blockIdx.x*256 + threadIdx.x;
  if (idx >= NN*1024) return;
  int r = idx >> 10, c = idx & 1023;
  Xb[idx] = (short)f2b(x[(size_t)r*1026 + 2 + c]);
}

// positional encodings into h0b cols 496..511
__global__ void pe_fill(const float* __restrict__ x, unsigned short* __restrict__ h0b){
  int r = blockIdx.x*256 + threadIdx.x;
  if (r >= NN) return;
  float p0 = x[(size_t)r*1026 + 0], p1 = x[(size_t)r*1026 + 1];
  const float dn[4] = {1.f, 10.f, 100.f, 1000.f};
  unsigned short* o = h0b + (size_t)r*512 + 496;
  #pragma unroll
  for (int q = 0; q < 4; ++q){
    o[2*q]     = f2b(sinf(p0/dn[q]));
    o[2*q+1]   = f2b(cosf(p0/dn[q]));
    o[8+2*q]   = f2b(sinf(p1/dn[q]));
    o[8+2*q+1] = f2b(cosf(p1/dn[q]));
  }
}

// ---------------- GEMM (A MxK bf16 row-major, Bt NpadxK bf16 row-major) ----------------
// 128x128 tile, 4 waves (2x2), each wave 64x64 via 4x4 mfma_f32_16x16x32_bf16 frags.
// Staging via global_load_lds width=16 (m97 pattern). LDS bank-conflict fix (T2,
// rule #21): linear LDS dest + PRE-SWIZZLED global source + swizzled ds_read.
// Slot (row, cblk) holds global colblock cblk ^ (((row mod 16)>>1)&3); reader XORs same.
// Unswizzled, 16 lanes of one lk hit 2 bank-quads (8-way, 2.94x — m136); swizzled,
// 2 lanes/bank (free). Measured before fix: 2^21 conflicts/dispatch.
#define GLDS(g, l) __builtin_amdgcn_global_load_lds((const __attribute__((address_space(1))) void*)(g), (__attribute__((address_space(3))) void*)(l), 16, 0, 0)

__global__ __launch_bounds__(256)
void gemm_bt(const short* __restrict__ A, const short* __restrict__ Bt,
             float* __restrict__ Cf, unsigned short* __restrict__ Cb,
             const float* __restrict__ bias, const float* __restrict__ resid,
             int K, int Nvalid, int epi){
  __shared__ __align__(16) short As[128*32];
  __shared__ __align__(16) short Bs[128*32];
  int tid = threadIdx.x;
  int m0 = blockIdx.x * 128;
  int n0 = blockIdx.y * 128;
  int lane = tid & 63, wave = tid >> 6;
  int wm = wave >> 1, wn = wave & 1;
  int lr = lane & 15, lk = lane >> 4;

  floatx4 acc[4][4];
  #pragma unroll
  for (int m = 0; m < 4; ++m)
    #pragma unroll
    for (int n = 0; n < 4; ++n) acc[m][n] = (floatx4)0.f;

  int wrow = wave * 32;          // wave's 32-row stripe of the tile
  int srow = lane >> 2;          // 0..15
  int sw   = (srow >> 1) & 3;    // row-swizzle key (same for srow and srow+16)
  int scol = ((lane & 3) ^ sw) * 8;  // pre-swizzled global colblock (elements)

  const short* gA0 = A  + (size_t)(m0 + wrow + srow)*K      + scol;
  const short* gA1 = A  + (size_t)(m0 + wrow + 16 + srow)*K + scol;
  const short* gB0 = Bt + (size_t)(n0 + wrow + srow)*K      + scol;
  const short* gB1 = Bt + (size_t)(n0 + wrow + 16 + srow)*K + scol;

  int cbs = (lk ^ ((lr >> 1) & 3)) * 8;   // swizzled read colblock (elements)

  for (int k0 = 0; k0 < K; k0 += 32){
    __syncthreads();
    GLDS(gA0 + k0, &As[wrow*32]);
    GLDS(gA1 + k0, &As[(wrow+16)*32]);
    GLDS(gB0 + k0, &Bs[wrow*32]);
    GLDS(gB1 + k0, &Bs[(wrow+16)*32]);
    __syncthreads();
    short8 af[4], bf[4];
    #pragma unroll
    for (int m = 0; m < 4; ++m) af[m] = *(const short8*)&As[(wm*64 + m*16 + lr)*32 + cbs];
    #pragma unroll
    for (int n = 0; n < 4; ++n) bf[n] = *(const short8*)&Bs[(wn*64 + n*16 + lr)*32 + cbs];
    #pragma unroll
    for (int m = 0; m < 4; ++m)
      #pragma unroll
      for (int n = 0; n < 4; ++n)
        acc[m][n] = __builtin_amdgcn_mfma_f32_16x16x32_bf16(af[m], bf[n], acc[m][n], 0, 0, 0);
  }

  #pragma unroll
  for (int m = 0; m < 4; ++m){
    #pragma unroll
    for (int n = 0; n < 4; ++n){
      int col = n0 + wn*64 + n*16 + lr;
      if (col < Nvalid){
        #pragma unroll
        for (int r = 0; r < 4; ++r){
          int row = m0 + wm*64 + m*16 + lk*4 + r;
          float v = acc[m][n][r];
          if (bias)  v += bias[col];
          if (resid) v += resid[(size_t)row*Nvalid + col];
          if (epi == 1) v = fmaxf(v, 0.f);
          else if (epi == 2) v = (v > 20.f) ? v : log1pf(expf(v));
          size_t o = (size_t)row*Nvalid + col;
          if (Cf) Cf[o] = v;
          if (Cb) Cb[o] = f2b(v);
        }
      }
    }
  }
}

// ---------------- attention scalars ----------------
__global__ void att_proj(const unsigned short* __restrict__ xh,
                         const float* __restrict__ att_src, const float* __restrict__ att_dst,
                         float* __restrict__ a_s, float* __restrict__ a_d){
  int wave = threadIdx.x >> 6, lane = threadIdx.x & 63;
  int r = blockIdx.x*4 + wave;
  const unsigned short* xr = xh + (size_t)r*512;
  float ps = 0.f, pd = 0.f;
  #pragma unroll
  for (int j = 0; j < 8; ++j){
    float v = b2f(xr[lane + 64*j]);
    ps += v * att_src[lane + 64*j];
    pd += v * att_dst[lane + 64*j];
  }
  #pragma unroll
  for (int m = 32; m >= 1; m >>= 1){ ps += __shfl_xor(ps, m); pd += __shfl_xor(pd, m); }
  if (lane == 0){ a_s[r] = ps; a_d[r] = pd; }
}

// ---------------- GAT bucketing ----------------
__global__ void gat_hist(const int* __restrict__ ei, int* __restrict__ cnt){
  int e = blockIdx.x*256 + threadIdx.x;
  if (e < EE) atomicAdd(&cnt[ei[EE + e]], 1);
}

__global__ void gat_prefix(const int* __restrict__ cnt, int* __restrict__ offsets, int* __restrict__ cursor){
  __shared__ int part[256];
  int t = threadIdx.x;
  int s = 0;
  for (int i = 0; i < 64; ++i) s += cnt[t*64 + i];
  part[t] = s;
  __syncthreads();
  for (int off = 1; off < 256; off <<= 1){
    int v = (t >= off) ? part[t - off] : 0;
    __syncthreads();
    part[t] += v;
    __syncthreads();
  }
  int run = part[t] - s;   // exclusive base
  for (int i = 0; i < 64; ++i){
    int c = cnt[t*64 + i];
    offsets[t*64 + i] = run;
    cursor[t*64 + i]  = run;
    run += c;
  }
  if (t == 255) offsets[NN] = run;
}

__global__ void gat_scatter(const int* __restrict__ ei, const float* __restrict__ a_s,
                            const float* __restrict__ a_d, int* __restrict__ cursor,
                            int* __restrict__ srcs, float* __restrict__ alphas){
  int e = blockIdx.x*256 + threadIdx.x;
  if (e >= EE) return;
  int sN = ei[e], dN = ei[EE + e];
  int p = atomicAdd(&cursor[dN], 1);
  srcs[p] = sN;
  float al = a_s[sN] + a_d[dN];
  alphas[p] = (al > 0.f) ? al : 0.2f*al;
}

// one wave per dst node: softmax over in-edges (+self loop), gather-weighted sum
__global__ __launch_bounds__(256)
void gat_agg(const int* __restrict__ offsets, const int* __restrict__ srcs,
             const float* __restrict__ alphas, const unsigned short* __restrict__ xh,
             const float* __restrict__ a_s, const float* __restrict__ a_d,
             const float* __restrict__ b_gat, float* __restrict__ gat){
  int wave = threadIdx.x >> 6, lane = threadIdx.x & 63;
  int i = blockIdx.x*4 + wave;
  int beg = offsets[i], end = offsets[i+1];
  float asd = a_s[i] + a_d[i];
  float al0 = (asd > 0.f) ? asd : 0.2f*asd;
  float mx = al0;
  for (int p = beg + lane; p < end; p += 64) mx = fmaxf(mx, alphas[p]);
  #pragma unroll
  for (int m = 32; m >= 1; m >>= 1) mx = fmaxf(mx, __shfl_xor(mx, m));
  float se = 0.f;
  for (int p = beg + lane; p < end; p += 64) se += __expf(alphas[p] - mx);
  #pragma unroll
  for (int m = 32; m >= 1; m >>= 1) se += __shfl_xor(se, m);
  float den = se + __expf(al0 - mx);
  float inv = 1.f/(den + 1e-16f);
  float acc[8] = {0,0,0,0,0,0,0,0};
  for (int p = beg; p < end; ++p){
    float w = __expf(alphas[p] - mx) * inv;
    const unsigned short* xr = xh + (size_t)srcs[p]*512;
    #pragma unroll
    for (int j = 0; j < 8; ++j) acc[j] += w * b2f(xr[lane + 64*j]);
  }
  {
    float w0 = __expf(al0 - mx) * inv;
    const unsigned short* xr = xh + (size_t)i*512;
    #pragma unroll
    for (int j = 0; j < 8; ++j) acc[j] += w0 * b2f(xr[lane + 64*j]);
  }
  #pragma unroll
  for (int j = 0; j < 8; ++j)
    gat[(size_t)i*512 + lane + 64*j] = acc[j] + b_gat[lane + 64*j];
}

// ---------------- conv + silu ----------------
__global__ void conv_silu(const unsigned short* __restrict__ xzb,
                          const float* __restrict__ w_conv, const float* __restrict__ b_conv,
                          float* __restrict__ xc, unsigned short* __restrict__ xcb){
  int r = blockIdx.x;
  int c = blockIdx.y*256 + threadIdx.x;
  int t = r & (LL - 1);
  float acc = b_conv[c];
  #pragma unroll
  for (int k = 0; k < 4; ++k){
    int tt = t + k - 3;
    if (tt >= 0) acc += b2f(xzb[(size_t)(r + k - 3)*1024 + c]) * w_conv[c*4 + k];
  }
  float s = acc / (1.f + __expf(-acc));
  xc[(size_t)r*512 + c] = s;
  xcb[(size_t)r*512 + c] = f2b(s);
}

// ---------------- SSM chunked parallel scan (s in registers) ----------------
// Thread per (b, chunk, d); all 16 state dims in VGPRs. Layout [bc][d][s].
__global__ __launch_bounds__(256)
void ssm_scan1(const float* __restrict__ dt, const float* __restrict__ xc,
               const float* __restrict__ BC, const float* __restrict__ A_log,
               float* __restrict__ Pc, float* __restrict__ Hc){
  int d  = blockIdx.y*256 + threadIdx.x;   // 0..511
  int bc = blockIdx.x;                     // b*NCK + ck
  int b  = bc >> 5;
  int ck = bc & (NCK - 1);
  float A[16], h[16];
  #pragma unroll
  for (int s = 0; s < 16; ++s){ A[s] = -__expf(A_log[d*16 + s]); h[s] = 0.f; }
  float sdt = 0.f;
  size_t r = (size_t)b*LL + (size_t)ck*TC;
  for (int t = 0; t < TC; ++t, ++r){
    float dtv = dt[r*512 + d];
    float xv  = xc[r*512 + d];
    float dx  = dtv * xv;
    const floatx4* bp = (const floatx4*)&BC[r*32];
    float Bf[16];
    *(floatx4*)&Bf[0]  = bp[0];
    *(floatx4*)&Bf[4]  = bp[1];
    *(floatx4*)&Bf[8]  = bp[2];
    *(floatx4*)&Bf[12] = bp[3];
    #pragma unroll
    for (int s = 0; s < 16; ++s){
      float a = __expf(dtv * A[s]);
      h[s] = h[s]*a + dx*Bf[s];
    }
    sdt += dtv;
  }
  size_t idx = ((size_t)bc*512 + d)*16;
  float P[16];
  #pragma unroll
  for (int s = 0; s < 16; ++s) P[s] = __expf(A[s]*sdt);   // prod(a) = exp(A*sum dt)
  #pragma unroll
  for (int q = 0; q < 4; ++q){
    *(floatx4*)&Pc[idx + q*4] = *(floatx4*)&P[q*4];
    *(floatx4*)&Hc[idx + q*4] = *(floatx4*)&h[q*4];
  }
}

// Carry pass: one thread per (b,d,s) stripe; sequential over 32 chunks.
// In-place: Hc[c] is overwritten with the chunk's INPUT carry.
__global__ void ssm_carry(const float* __restrict__ Pc, float* __restrict__ Hc){
  int gid = blockIdx.x*256 + threadIdx.x;   // 0..65535
  int b  = gid >> 13;                       // 512*16 = 8192 stripes per batch
  int ds = gid & 8191;
  size_t idx = ((size_t)b*NCK)*8192 + ds;
  float carry = 0.f;
  for (int c = 0; c < NCK; ++c){
    float P = Pc[idx], H = Hc[idx];
    Hc[idx] = carry;
    carry = H + P*carry;
    idx += 8192;
  }
}

// Pass 2: re-scan each chunk from its true carry-in; emit gated output.
__global__ __launch_bounds__(256)
void ssm_scan2(const float* __restrict__ dt, const float* __restrict__ xc,
               const float* __restrict__ BC, const unsigned short* __restrict__ xzb,
               const float* __restrict__ A_log, const float* __restrict__ D_p,
               const float* __restrict__ Cin, unsigned short* __restrict__ yfb){
  int d  = blockIdx.y*256 + threadIdx.x;
  int bc = blockIdx.x;
  int b  = bc >> 5;
  int ck = bc & (NCK - 1);
  float A[16], h[16];
  size_t idx = ((size_t)bc*512 + d)*16;
  #pragma unroll
  for (int s = 0; s < 16; ++s){ A[s] = -__expf(A_log[d*16 + s]); h[s] = Cin[idx + s]; }
  float Dp = D_p[d];
  size_t r = (size_t)b*LL + (size_t)ck*TC;
  for (int t = 0; t < TC; ++t, ++r){
    float dtv = dt[r*512 + d];
    float xv  = xc[r*512 + d];
    float dx  = dtv * xv;
    const floatx4* bp = (const floatx4*)&BC[r*32];
    float Bf[16], Cf[16];
    *(floatx4*)&Bf[0]  = bp[0];
    *(floatx4*)&Bf[4]  = bp[1];
    *(floatx4*)&Bf[8]  = bp[2];
    *(floatx4*)&Bf[12] = bp[3];
    *(floatx4*)&Cf[0]  = bp[4];
    *(floatx4*)&Cf[4]  = bp[5];
    *(floatx4*)&Cf[8]  = bp[6];
    *(floatx4*)&Cf[12] = bp[7];
    float y = 0.f;
    #pragma unroll
    for (int s = 0; s < 16; ++s){
      float a = __expf(dtv * A[s]);
      h[s] = h[s]*a + dx*Bf[s];
      y += h[s]*Cf[s];
    }
    float z  = b2f(xzb[r*1024 + 512 + d]);
    float sz = z / (1.f + __expf(-z));
    yfb[r*512 + d] = f2b((y + Dp*xv) * sz);
  }
}

// ---------------- column stats (sum, sumsq) ----------------
__global__ void colstats(const float* __restrict__ X, float* __restrict__ sums, float* __restrict__ sqs){
  int c0 = threadIdx.x;
  int row0 = blockIdx.x * 128;
  float s0=0,q0=0,s1=0,q1=0;
  for (int i = 0; i < 128; ++i){
    const float* rp = X + (size_t)(row0+i)*512;
    float a = rp[c0], b = rp[c0+256];
    s0 += a; q0 += a*a; s1 += b; q1 += b*b;
  }
  atomicAdd(&sums[c0], s0);      atomicAdd(&sqs[c0], q0);
  atomicAdd(&sums[c0+256], s1);  atomicAdd(&sqs[c0+256], q1);
}

// out0 = BN(gat)*g1+be1 + BN(h2)*g2+be2  (f32 + bf16)
__global__ void combine_out0(const float* __restrict__ gat, const float* __restrict__ h2,
                             const float* __restrict__ s1, const float* __restrict__ q1,
                             const float* __restrict__ s2, const float* __restrict__ q2,
                             const float* __restrict__ g1, const float* __restrict__ be1,
                             const float* __restrict__ g2, const float* __restrict__ be2,
                             float* __restrict__ out0, unsigned short* __restrict__ out0b){
  int t = threadIdx.x;
  int row0 = blockIdx.x * 128;
  const float invN = 1.f/16384.f;
  float sc1[2], sc2[2], off[2];
  #pragma unroll
  for (int h = 0; h < 2; ++h){
    int c = t + h*256;
    float m1 = s1[c]*invN, v1 = q1[c]*invN - m1*m1;
    float m2 = s2[c]*invN, v2 = q2[c]*invN - m2*m2;
    float a1 = rsqrtf(v1 + 1e-5f) * g1[c];
    float a2 = rsqrtf(v2 + 1e-5f) * g2[c];
    sc1[h] = a1; sc2[h] = a2;
    off[h] = be1[c] + be2[c] - m1*a1 - m2*a2;
  }
  for (int i = 0; i < 128; ++i){
    size_t ro = (size_t)(row0+i)*512;
    #pragma unroll
    for (int h = 0; h < 2; ++h){
      int c = t + h*256;
      float v = gat[ro+c]*sc1[h] + h2[ro+c]*sc2[h] + off[h];
      out0[ro+c] = v;
      out0b[ro+c] = f2b(v);
    }
  }
}

// out2 = relu(BN(out1)*g3+be3); per-batch column sums -> poolsum
__global__ void out2_pool(const float* __restrict__ out1,
                          const float* __restrict__ s3, const float* __restrict__ q3,
                          const float* __restrict__ g3, const float* __restrict__ be3,
                          float* __restrict__ poolsum){
  int t = threadIdx.x;
  int row0 = blockIdx.x * 128;
  int bidx = row0 / LL;
  const float invN = 1.f/16384.f;
  float sc[2], off[2], acc[2] = {0.f, 0.f};
  #pragma unroll
  for (int h = 0; h < 2; ++h){
    int c = t + h*256;
    float m = s3[c]*invN, v = q3[c]*invN - m*m;
    float a = rsqrtf(v + 1e-5f) * g3[c];
    sc[h] = a; off[h] = be3[c] - m*a;
  }
  for (int i = 0; i < 128; ++i){
    size_t ro = (size_t)(row0+i)*512;
    #pragma unroll
    for (int h = 0; h < 2; ++h){
      int c = t + h*256;
      float v = fmaxf(out1[ro+c]*sc[h] + off[h], 0.f);
      acc[h] += v;
    }
  }
  atomicAdd(&poolsum[bidx*512 + t], acc[0]);
  atomicAdd(&poolsum[bidx*512 + t + 256], acc[1]);
}

// final head MLP: one block per batch row
__global__ __launch_bounds__(256)
void head(const float* __restrict__ poolsum,
          const float* __restrict__ Wf1, const float* __restrict__ bf1,
          const float* __restrict__ Wf2, const float* __restrict__ bf2,
          const float* __restrict__ Wf3, const float* __restrict__ bf3,
          float* __restrict__ dout){
  int r = blockIdx.x, t = threadIdx.x;
  __shared__ float pool[512];
  __shared__ float h1s[256];
  __shared__ float h2s[128];
  for (int i = t; i < 512; i += 256){
    float v = poolsum[r*512 + i] * (1.f/2048.f);
    pool[i] = v;
    dout[8 + r*512 + i] = v;
  }
  __syncthreads();
  {
    float a = bf1[t];
    for (int k = 0; k < 512; ++k) a += pool[k] * Wf1[(size_t)k*256 + t];
    h1s[t] = fmaxf(a, 0.f);
  }
  __syncthreads();
  if (t < 128){
    float a = bf2[t];
    for (int k = 0; k < 256; ++k) a += h1s[k] * Wf2[(size_t)k*128 + t];
    h2s[t] = fmaxf(a, 0.f);
  }
  __syncthreads();
  if (t == 0){
    float a = bf3[0];
    for (int k = 0; k < 128; ++k) a += h2s[k] * Wf3[k];
    dout[r] = a;
  }
}

// ---------------- host ----------------
extern "C" void kernel_launch(void* const* d_in, const int* in_sizes, int n_in,
                              void* d_out, int out_size, void* d_ws, size_t ws_size,
                              hipStream_t stream){
  const float* x      = (const float*)d_in[0];
  const int*   ei     = (const int*)d_in[1];
  const float* W_uni  = (const float*)d_in[5];
  const float* b_uni  = (const float*)d_in[6];
  const float* W_gat  = (const float*)d_in[10];
  const float* att_s  = (const float*)d_in[11];
  const float* att_d  = (const float*)d_in[12];
  const float* b_gat  = (const float*)d_in[13];
  const float* g1     = (const float*)d_in[14];
  const float* be1    = (const float*)d_in[15];
  const float* g2     = (const float*)d_in[16];
  const float* be2    = (const float*)d_in[17];
  const float* g3     = (const float*)d_in[18];
  const float* be3    = (const float*)d_in[19];
  const float* W_in   = (const float*)d_in[20];
  const float* w_conv = (const float*)d_in[21];
  const float* b_conv = (const float*)d_in[22];
  const float* W_xp   = (const float*)d_in[23];
  const float* W_dt   = (const float*)d_in[24];
  const float* b_dt   = (const float*)d_in[25];
  const float* A_log  = (const float*)d_in[26];
  const float* D_p    = (const float*)d_in[27];
  const float* W_out  = (const float*)d_in[28];
  const float* W_m1   = (const float*)d_in[29];
  const float* b_m1   = (const float*)d_in[30];
  const float* W_m2   = (const float*)d_in[31];
  const float* b_m2   = (const float*)d_in[32];
  const float* Wf1    = (const float*)d_in[33];
  const float* bf1    = (const float*)d_in[34];
  const float* Wf2    = (const float*)d_in[35];
  const float* bf2    = (const float*)d_in[36];
  const float* Wf3    = (const float*)d_in[37];
  const float* bf3    = (const float*)d_in[38];
  float* dout = (float*)d_out;

  char* base = (char*)d_ws;
  size_t off = 0;
  auto alloc = [&](size_t b){ size_t r = off; off += (b + 255) & ~(size_t)255; return r; };

  size_t oR1    = alloc((size_t)NN*1024*2);   // Xb -> xzb -> out1 (33.5MB each, aliased)
  size_t oH0b   = alloc((size_t)NN*512*2);    // h0b bf16
  size_t oWuniT = alloc(512*1024*2);
  size_t oWgatT = alloc(512*512*2);
  size_t oWinT  = alloc(1024*512*2);
  size_t oWfusT = alloc(512*512*2);
  size_t oWbcT  = alloc(128*512*2);
  size_t oWoutT = alloc(512*512*2);
  size_t oWm1T  = alloc(1024*512*2);
  size_t oWm2T  = alloc(512*1024*2);
  size_t oBuni  = alloc(512*4);
  size_t oXh    = alloc((size_t)NN*512*2);    // xh bf16 -> yfb bf16
  size_t oAs    = alloc(NN*4);
  size_t oAd    = alloc(NN*4);
  size_t oCnt   = alloc(NN*4);
  size_t oCur   = alloc(NN*4);
  size_t oOff   = alloc((NN+1)*4);
  size_t oSrcs  = alloc((size_t)EE*4);
  size_t oAlph  = alloc((size_t)EE*4);
  size_t oGat   = alloc((size_t)NN*512*4);    // gat f32 -> mlp1b bf16
  size_t oXc    = alloc((size_t)NN*512*4);    // xc f32 -> out0 f32
  size_t oXcb   = alloc((size_t)NN*512*2);    // xcb bf16 -> Pc/Hc f32 (scan) -> out0b bf16
  size_t oDt    = alloc((size_t)NN*512*4);    // dt f32 -> h2raw f32
  size_t oBC    = alloc((size_t)NN*32*4);
  size_t oStats = alloc(6*512*4);             // s1,q1,s2,q2,s3,q3
  size_t oPool  = alloc(8*512*4);

  short* Xb   = (short*)(base + oR1);
  unsigned short* xzb = (unsigned short*)(base + oR1);
  float* out1 = (float*)(base + oR1);
  unsigned short* h0b = (unsigned short*)(base + oH0b);
  short* WuniT = (short*)(base + oWuniT);
  short* WgatT = (short*)(base + oWgatT);
  short* WinT  = (short*)(base + oWinT);
  short* WfusT = (short*)(base + oWfusT);
  short* WbcT  = (short*)(base + oWbcT);
  short* WoutT = (short*)(base + oWoutT);
  short* Wm1T  = (short*)(base + oWm1T);
  short* Wm2T  = (short*)(base + oWm2T);
  float* buniP = (float*)(base + oBuni);
  unsigned short* xh  = (unsigned short*)(base + oXh);
  unsigned short* yfb = (unsigned short*)(base + oXh);
  float* a_s = (float*)(base + oAs);
  float* a_d = (float*)(base + oAd);
  int* cnt = (int*)(base + oCnt);
  int* cur = (int*)(base + oCur);
  int* offs = (int*)(base + oOff);
  int* srcs = (int*)(base + oSrcs);
  float* alphas = (float*)(base + oAlph);
  float* gat = (float*)(base + oGat);
  unsigned short* mlp1b = (unsigned short*)(base + oGat);
  float* xc = (float*)(base + oXc);
  float* out0 = (float*)(base + oXc);
  unsigned short* xcb  = (unsigned short*)(base + oXcb);
  unsigned short* out0b = (unsigned short*)(base + oXcb);
  // scan scratch aliases the xcb region (dead between BC-GEMM and combine_out0):
  // Pc = 8*32*512*16 f32 = 8 MB, Hc same; total 16 MB <= 16.78 MB region.
  float* Pc = (float*)(base + oXcb);
  float* Hc = Pc + (size_t)8*NCK*512*16;
  float* dt = (float*)(base + oDt);
  float* h2raw = (float*)(base + oDt);
  float* BC = (float*)(base + oBC);
  float* s1 = (float*)(base + oStats);
  float* q1 = s1 + 512;
  float* s2 = q1 + 512;
  float* q2 = s2 + 512;
  float* s3 = q2 + 512;
  float* q3 = s3 + 512;
  float* poolsum = (float*)(base + oPool);

  // zero the accumulators
  hipMemsetAsync(cnt, 0, NN*4, stream);
  hipMemsetAsync(s1, 0, 6*512*4, stream);
  hipMemsetAsync(poolsum, 0, 8*512*4, stream);

  // prep: convert/transpose weights, convert x, fuse W_xp@W_dt
  transposeW<<<(512*1024+255)/256, 256, 0, stream>>>(W_uni, WuniT, 1024, 496, 512, 496, 0);
  transposeW<<<(512*512+255)/256, 256, 0, stream>>>(W_gat, WgatT, 512, 512, 512, 512, 0);
  transposeW<<<(1024*512+255)/256, 256, 0, stream>>>(W_in, WinT, 512, 1024, 1024, 1024, 0);
  transposeW<<<(128*512+255)/256, 256, 0, stream>>>(W_xp, WbcT, 512, 32, 128, 64, 32);
  transposeW<<<(512*512+255)/256, 256, 0, stream>>>(W_out, WoutT, 512, 512, 512, 512, 0);
  transposeW<<<(1024*512+255)/256, 256, 0, stream>>>(W_m1, Wm1T, 512, 1024, 1024, 1024, 0);
  transposeW<<<(512*1024+255)/256, 256, 0, stream>>>(W_m2, Wm2T, 1024, 512, 512, 512, 0);
  fuse_wdt<<<(512*512+255)/256, 256, 0, stream>>>(W_xp, W_dt, WfusT);
  pad_bias<<<2, 256, 0, stream>>>(b_uni, buniP);
  conv_x<<<(NN*1024+255)/256, 256, 0, stream>>>(x, Xb);

  dim3 g4(128, 4), g8(128, 8), g1b(128, 1);
  // h0 = [x@W_uni + b_uni | pe]
  gemm_bt<<<g4, 256, 0, stream>>>(Xb, WuniT, nullptr, h0b, buniP, nullptr, 1024, 512, 0);
  pe_fill<<<(NN+255)/256, 256, 0, stream>>>(x, h0b);
  // xh = h0 @ W_gat  (bf16)
  gemm_bt<<<g4, 256, 0, stream>>>((const short*)h0b, WgatT, nullptr, xh, nullptr, nullptr, 512, 512, 0);
  att_proj<<<NN/4, 256, 0, stream>>>(xh, att_s, att_d, a_s, a_d);
  // GAT
  gat_hist<<<EE/256, 256, 0, stream>>>(ei, cnt);
  gat_prefix<<<1, 256, 0, stream>>>(cnt, offs, cur);
  gat_scatter<<<EE/256, 256, 0, stream>>>(ei, a_s, a_d, cur, srcs, alphas);
  gat_agg<<<NN/4, 256, 0, stream>>>(offs, srcs, alphas, xh, a_s, a_d, b_gat, gat);
  colstats<<<128, 256, 0, stream>>>(gat, s1, q1);
  // Mamba path
  gemm_bt<<<g8, 256, 0, stream>>>((const short*)h0b, WinT, nullptr, xzb, nullptr, nullptr, 512, 1024, 0);
  {
    dim3 gc(NN, 2);
    conv_silu<<<gc, 256, 0, stream>>>(xzb, w_conv, b_conv, xc, xcb);
  }
  gemm_bt<<<g4, 256, 0, stream>>>((const short*)xcb, WfusT, dt, nullptr, b_dt, nullptr, 512, 512, 2);
  gemm_bt<<<g1b, 256, 0, stream>>>((const short*)xcb, WbcT, BC, nullptr, nullptr, nullptr, 512, 32, 0);
  // chunked parallel scan (xcb region is dead from here until combine_out0)
  {
    dim3 gs(8*NCK, 2);
    ssm_scan1<<<gs, 256, 0, stream>>>(dt, xc, BC, A_log, Pc, Hc);
    ssm_carry<<<256, 256, 0, stream>>>(Pc, Hc);
    ssm_scan2<<<gs, 256, 0, stream>>>(dt, xc, BC, xzb, A_log, D_p, Hc, yfb);
  }
  gemm_bt<<<g4, 256, 0, stream>>>((const short*)yfb, WoutT, h2raw, nullptr, nullptr, nullptr, 512, 512, 0);
  colstats<<<128, 256, 0, stream>>>(h2raw, s2, q2);
  // combine + MLP residual
  combine_out0<<<128, 256, 0, stream>>>(gat, h2raw, s1, q1, s2, q2, g1, be1, g2, be2, out0, out0b);
  gemm_bt<<<g8, 256, 0, stream>>>((const short*)out0b, Wm1T, nullptr, mlp1b, b_m1, nullptr, 512, 1024, 1);
  gemm_bt<<<g4, 256, 0, stream>>>((const short*)mlp1b, Wm2T, out1, nullptr, b_m2, out0, 1024, 512, 0);
  colstats<<<128, 256, 0, stream>>>(out1, s3, q3);
  out2_pool<<<128, 256, 0, stream>>>(out1, s3, q3, g3, be3, poolsum);
  head<<<8, 256, 0, stream>>>(poolsum, Wf1, bf1, Wf2, bf2, Wf3, bf3, dout);
}

// Round 13
// 901.799 us; speedup vs baseline: 2.6916x; 1.0082x over previous
//
#include <hip/hip_runtime.h>
#include <math.h>

#define NN 16384
#define CD 512
#define EE 262144
#define LL 2048
#define NCK 32   // time chunks per batch
#define TC 64    // steps per chunk

typedef __attribute__((ext_vector_type(8))) short short8;
typedef __attribute__((ext_vector_type(4))) float floatx4;

__device__ __forceinline__ unsigned short f2b(float f){
  unsigned int u = __float_as_uint(f);
  unsigned int r = (u + 0x7fffu + ((u>>16)&1u)) >> 16;
  return (unsigned short)r;
}
__device__ __forceinline__ float b2f(unsigned short h){
  return __uint_as_float(((unsigned int)h)<<16);
}

// ---------------- prep kernels ----------------

// W: K x Nsub (row pitch `pitch`, col offset col0) -> Bt: Npad x K bf16 (zero-padded rows)
__global__ void transposeW(const float* __restrict__ W, short* __restrict__ Bt,
                           int K, int Nsub, int Npad, int pitch, int col0){
  int idx = blockIdx.x*256 + threadIdx.x;
  if (idx >= Npad*K) return;
  int n = idx / K, k = idx - n*K;
  float v = (n < Nsub) ? W[(size_t)k*pitch + col0 + n] : 0.f;
  Bt[idx] = (short)f2b(v);
}

// Wfused^T[j][i] = sum_r W_xp[i,r]*W_dt[r,j]  (512x512 bf16, Bt layout)
__global__ void fuse_wdt(const float* __restrict__ W_xp, const float* __restrict__ W_dt,
                         short* __restrict__ Wft){
  int idx = blockIdx.x*256 + threadIdx.x;   // 512*512
  if (idx >= 512*512) return;
  int i = idx & 511;      // input channel (k-dim)
  int j = idx >> 9;       // output channel
  float a = 0.f;
  #pragma unroll 8
  for (int r = 0; r < 32; ++r) a += W_xp[(size_t)i*64 + r] * W_dt[(size_t)r*512 + j];
  Wft[idx] = (short)f2b(a);
}

__global__ void pad_bias(const float* __restrict__ b, float* __restrict__ out){
  int i = blockIdx.x*256 + threadIdx.x;
  if (i < 512) out[i] = (i < 496) ? b[i] : 0.f;
}

// x (16384 x 1026) cols 2..1025 -> Xb bf16 (16384 x 1024)
__global__ void conv_x(const float* __restrict__ x, short* __restrict__ Xb){
  int idx = blockIdx.x*256 + threadIdx.x;
  if (idx >= NN*1024) return;
  int r = idx >> 10, c = idx & 1023;
  Xb[idx] = (short)f2b(x[(size_t)r*1026 + 2 + c]);
}

// positional encodings into h0b cols 496..511
__global__ void pe_fill(const float* __restrict__ x, unsigned short* __restrict__ h0b){
  int r = blockIdx.x*256 + threadIdx.x;
  if (r >= NN) return;
  float p0 = x[(size_t)r*1026 + 0], p1 = x[(size_t)r*1026 + 1];
  const float dn[4] = {1.f, 10.f, 100.f, 1000.f};
  unsigned short* o = h0b + (size_t)r*512 + 496;
  #pragma unroll
  for (int q = 0; q < 4; ++q){
    o[2*q]     = f2b(sinf(p0/dn[q]));
    o[2*q+1]   = f2b(cosf(p0/dn[q]));
    o[8+2*q]   = f2b(sinf(p1/dn[q]));
    o[8+2*q+1] = f2b(cosf(p1/dn[q]));
  }
}

// ---------------- GEMM (A MxK bf16 row-major, Bt NpadxK bf16 row-major) ----------------
// 128x128 tile, 4 waves (2x2), each wave 64x64 via 4x4 mfma_f32_16x16x32_bf16 frags.
// T2 swizzle (r10: conflicts 2^21 -> 0) + T3 minimum 2-phase double-buffer:
// prologue stages buf0; each iter issues prefetch->buf(cur^1) BEFORE computing
// buf(cur); the single __syncthreads() (implicit vmcnt(0)+lgkmcnt(0) drain) lands
// the prefetch that had the whole MFMA phase to fly. One barrier/K-step, load
// latency hidden under compute (r10 counters: 9% MfmaUtil, serial load->compute).
#define GLDS(g, l) __builtin_amdgcn_global_load_lds((const __attribute__((address_space(1))) void*)(g), (__attribute__((address_space(3))) void*)(l), 16, 0, 0)

__global__ __launch_bounds__(256)
void gemm_bt(const short* __restrict__ A, const short* __restrict__ Bt,
             float* __restrict__ Cf, unsigned short* __restrict__ Cb,
             const float* __restrict__ bias, const float* __restrict__ resid,
             int K, int Nvalid, int epi){
  __shared__ __align__(16) short As[2][128*32];
  __shared__ __align__(16) short Bs[2][128*32];
  int tid = threadIdx.x;
  int m0 = blockIdx.x * 128;
  int n0 = blockIdx.y * 128;
  int lane = tid & 63, wave = tid >> 6;
  int wm = wave >> 1, wn = wave & 1;
  int lr = lane & 15, lk = lane >> 4;

  floatx4 acc[4][4];
  #pragma unroll
  for (int m = 0; m < 4; ++m)
    #pragma unroll
    for (int n = 0; n < 4; ++n) acc[m][n] = (floatx4)0.f;

  int wrow = wave * 32;          // wave's 32-row stripe of the tile
  int srow = lane >> 2;          // 0..15
  int sw   = (srow >> 1) & 3;    // row-swizzle key (same for srow and srow+16)
  int scol = ((lane & 3) ^ sw) * 8;  // pre-swizzled global colblock (elements)

  const short* gA0 = A  + (size_t)(m0 + wrow + srow)*K      + scol;
  const short* gA1 = A  + (size_t)(m0 + wrow + 16 + srow)*K + scol;
  const short* gB0 = Bt + (size_t)(n0 + wrow + srow)*K      + scol;
  const short* gB1 = Bt + (size_t)(n0 + wrow + 16 + srow)*K + scol;

  int cbs = (lk ^ ((lr >> 1) & 3)) * 8;   // swizzled read colblock (elements)

  auto stage = [&](int buf, int k0){
    GLDS(gA0 + k0, &As[buf][wrow*32]);
    GLDS(gA1 + k0, &As[buf][(wrow+16)*32]);
    GLDS(gB0 + k0, &Bs[buf][wrow*32]);
    GLDS(gB1 + k0, &Bs[buf][(wrow+16)*32]);
  };
  auto compute = [&](int buf){
    short8 af[4], bf[4];
    #pragma unroll
    for (int m = 0; m < 4; ++m) af[m] = *(const short8*)&As[buf][(wm*64 + m*16 + lr)*32 + cbs];
    #pragma unroll
    for (int n = 0; n < 4; ++n) bf[n] = *(const short8*)&Bs[buf][(wn*64 + n*16 + lr)*32 + cbs];
    #pragma unroll
    for (int m = 0; m < 4; ++m)
      #pragma unroll
      for (int n = 0; n < 4; ++n)
        acc[m][n] = __builtin_amdgcn_mfma_f32_16x16x32_bf16(af[m], bf[n], acc[m][n], 0, 0, 0);
  };

  // prologue: stage tile 0 into buf 0; barrier drains vmcnt(0)
  stage(0, 0);
  __syncthreads();
  int cur = 0;
  for (int k0 = 32; k0 < K; k0 += 32){
    stage(cur ^ 1, k0);     // prefetch next tile (latency hides under compute)
    compute(cur);
    __syncthreads();        // drains prefetch vmcnt + guards buffer reuse
    cur ^= 1;
  }
  compute(cur);             // epilogue: last tile, no prefetch

  #pragma unroll
  for (int m = 0; m < 4; ++m){
    #pragma unroll
    for (int n = 0; n < 4; ++n){
      int col = n0 + wn*64 + n*16 + lr;
      if (col < Nvalid){
        #pragma unroll
        for (int r = 0; r < 4; ++r){
          int row = m0 + wm*64 + m*16 + lk*4 + r;
          float v = acc[m][n][r];
          if (bias)  v += bias[col];
          if (resid) v += resid[(size_t)row*Nvalid + col];
          if (epi == 1) v = fmaxf(v, 0.f);
          else if (epi == 2) v = (v > 20.f) ? v : log1pf(expf(v));
          size_t o = (size_t)row*Nvalid + col;
          if (Cf) Cf[o] = v;
          if (Cb) Cb[o] = f2b(v);
        }
      }
    }
  }
}

// ---------------- attention scalars ----------------
__global__ void att_proj(const unsigned short* __restrict__ xh,
                         const float* __restrict__ att_src, const float* __restrict__ att_dst,
                         float* __restrict__ a_s, float* __restrict__ a_d){
  int wave = threadIdx.x >> 6, lane = threadIdx.x & 63;
  int r = blockIdx.x*4 + wave;
  const unsigned short* xr = xh + (size_t)r*512;
  float ps = 0.f, pd = 0.f;
  #pragma unroll
  for (int j = 0; j < 8; ++j){
    float v = b2f(xr[lane + 64*j]);
    ps += v * att_src[lane + 64*j];
    pd += v * att_dst[lane + 64*j];
  }
  #pragma unroll
  for (int m = 32; m >= 1; m >>= 1){ ps += __shfl_xor(ps, m); pd += __shfl_xor(pd, m); }
  if (lane == 0){ a_s[r] = ps; a_d[r] = pd; }
}

// ---------------- GAT bucketing ----------------
__global__ void gat_hist(const int* __restrict__ ei, int* __restrict__ cnt){
  int e = blockIdx.x*256 + threadIdx.x;
  if (e < EE) atomicAdd(&cnt[ei[EE + e]], 1);
}

__global__ void gat_prefix(const int* __restrict__ cnt, int* __restrict__ offsets, int* __restrict__ cursor){
  __shared__ int part[256];
  int t = threadIdx.x;
  int s = 0;
  for (int i = 0; i < 64; ++i) s += cnt[t*64 + i];
  part[t] = s;
  __syncthreads();
  for (int off = 1; off < 256; off <<= 1){
    int v = (t >= off) ? part[t - off] : 0;
    __syncthreads();
    part[t] += v;
    __syncthreads();
  }
  int run = part[t] - s;   // exclusive base
  for (int i = 0; i < 64; ++i){
    int c = cnt[t*64 + i];
    offsets[t*64 + i] = run;
    cursor[t*64 + i]  = run;
    run += c;
  }
  if (t == 255) offsets[NN] = run;
}

__global__ void gat_scatter(const int* __restrict__ ei, const float* __restrict__ a_s,
                            const float* __restrict__ a_d, int* __restrict__ cursor,
                            int* __restrict__ srcs, float* __restrict__ alphas){
  int e = blockIdx.x*256 + threadIdx.x;
  if (e >= EE) return;
  int sN = ei[e], dN = ei[EE + e];
  int p = atomicAdd(&cursor[dN], 1);
  srcs[p] = sN;
  float al = a_s[sN] + a_d[dN];
  alphas[p] = (al > 0.f) ? al : 0.2f*al;
}

// one wave per dst node: softmax over in-edges (+self loop), gather-weighted sum
__global__ __launch_bounds__(256)
void gat_agg(const int* __restrict__ offsets, const int* __restrict__ srcs,
             const float* __restrict__ alphas, const unsigned short* __restrict__ xh,
             const float* __restrict__ a_s, const float* __restrict__ a_d,
             const float* __restrict__ b_gat, float* __restrict__ gat){
  int wave = threadIdx.x >> 6, lane = threadIdx.x & 63;
  int i = blockIdx.x*4 + wave;
  int beg = offsets[i], end = offsets[i+1];
  float asd = a_s[i] + a_d[i];
  float al0 = (asd > 0.f) ? asd : 0.2f*asd;
  float mx = al0;
  for (int p = beg + lane; p < end; p += 64) mx = fmaxf(mx, alphas[p]);
  #pragma unroll
  for (int m = 32; m >= 1; m >>= 1) mx = fmaxf(mx, __shfl_xor(mx, m));
  float se = 0.f;
  for (int p = beg + lane; p < end; p += 64) se += __expf(alphas[p] - mx);
  #pragma unroll
  for (int m = 32; m >= 1; m >>= 1) se += __shfl_xor(se, m);
  float den = se + __expf(al0 - mx);
  float inv = 1.f/(den + 1e-16f);
  float acc[8] = {0,0,0,0,0,0,0,0};
  for (int p = beg; p < end; ++p){
    float w = __expf(alphas[p] - mx) * inv;
    const unsigned short* xr = xh + (size_t)srcs[p]*512;
    #pragma unroll
    for (int j = 0; j < 8; ++j) acc[j] += w * b2f(xr[lane + 64*j]);
  }
  {
    float w0 = __expf(al0 - mx) * inv;
    const unsigned short* xr = xh + (size_t)i*512;
    #pragma unroll
    for (int j = 0; j < 8; ++j) acc[j] += w0 * b2f(xr[lane + 64*j]);
  }
  #pragma unroll
  for (int j = 0; j < 8; ++j)
    gat[(size_t)i*512 + lane + 64*j] = acc[j] + b_gat[lane + 64*j];
}

// ---------------- conv + silu ----------------
__global__ void conv_silu(const unsigned short* __restrict__ xzb,
                          const float* __restrict__ w_conv, const float* __restrict__ b_conv,
                          float* __restrict__ xc, unsigned short* __restrict__ xcb){
  int r = blockIdx.x;
  int c = blockIdx.y*256 + threadIdx.x;
  int t = r & (LL - 1);
  float acc = b_conv[c];
  #pragma unroll
  for (int k = 0; k < 4; ++k){
    int tt = t + k - 3;
    if (tt >= 0) acc += b2f(xzb[(size_t)(r + k - 3)*1024 + c]) * w_conv[c*4 + k];
  }
  float s = acc / (1.f + __expf(-acc));
  xc[(size_t)r*512 + c] = s;
  xcb[(size_t)r*512 + c] = f2b(s);
}

// ---------------- SSM chunked parallel scan (s in registers) ----------------
// Thread per (b, chunk, d); all 16 state dims in VGPRs. Layout [bc][d][s].
__global__ __launch_bounds__(256)
void ssm_scan1(const float* __restrict__ dt, const float* __restrict__ xc,
               const float* __restrict__ BC, const float* __restrict__ A_log,
               float* __restrict__ Pc, float* __restrict__ Hc){
  int d  = blockIdx.y*256 + threadIdx.x;   // 0..511
  int bc = blockIdx.x;                     // b*NCK + ck
  int b  = bc >> 5;
  int ck = bc & (NCK - 1);
  float A[16], h[16];
  #pragma unroll
  for (int s = 0; s < 16; ++s){ A[s] = -__expf(A_log[d*16 + s]); h[s] = 0.f; }
  float sdt = 0.f;
  size_t r = (size_t)b*LL + (size_t)ck*TC;
  for (int t = 0; t < TC; ++t, ++r){
    float dtv = dt[r*512 + d];
    float xv  = xc[r*512 + d];
    float dx  = dtv * xv;
    const floatx4* bp = (const floatx4*)&BC[r*32];
    float Bf[16];
    *(floatx4*)&Bf[0]  = bp[0];
    *(floatx4*)&Bf[4]  = bp[1];
    *(floatx4*)&Bf[8]  = bp[2];
    *(floatx4*)&Bf[12] = bp[3];
    #pragma unroll
    for (int s = 0; s < 16; ++s){
      float a = __expf(dtv * A[s]);
      h[s] = h[s]*a + dx*Bf[s];
    }
    sdt += dtv;
  }
  size_t idx = ((size_t)bc*512 + d)*16;
  float P[16];
  #pragma unroll
  for (int s = 0; s < 16; ++s) P[s] = __expf(A[s]*sdt);   // prod(a) = exp(A*sum dt)
  #pragma unroll
  for (int q = 0; q < 4; ++q){
    *(floatx4*)&Pc[idx + q*4] = *(floatx4*)&P[q*4];
    *(floatx4*)&Hc[idx + q*4] = *(floatx4*)&h[q*4];
  }
}

// Carry pass: one thread per (b,d,s) stripe; sequential over 32 chunks.
// In-place: Hc[c] is overwritten with the chunk's INPUT carry.
__global__ void ssm_carry(const float* __restrict__ Pc, float* __restrict__ Hc){
  int gid = blockIdx.x*256 + threadIdx.x;   // 0..65535
  int b  = gid >> 13;                       // 512*16 = 8192 stripes per batch
  int ds = gid & 8191;
  size_t idx = ((size_t)b*NCK)*8192 + ds;
  float carry = 0.f;
  for (int c = 0; c < NCK; ++c){
    float P = Pc[idx], H = Hc[idx];
    Hc[idx] = carry;
    carry = H + P*carry;
    idx += 8192;
  }
}

// Pass 2: re-scan each chunk from its true carry-in; emit gated output.
__global__ __launch_bounds__(256)
void ssm_scan2(const float* __restrict__ dt, const float* __restrict__ xc,
               const float* __restrict__ BC, const unsigned short* __restrict__ xzb,
               const float* __restrict__ A_log, const float* __restrict__ D_p,
               const float* __restrict__ Cin, unsigned short* __restrict__ yfb){
  int d  = blockIdx.y*256 + threadIdx.x;
  int bc = blockIdx.x;
  int b  = bc >> 5;
  int ck = bc & (NCK - 1);
  float A[16], h[16];
  size_t idx = ((size_t)bc*512 + d)*16;
  #pragma unroll
  for (int s = 0; s < 16; ++s){ A[s] = -__expf(A_log[d*16 + s]); h[s] = Cin[idx + s]; }
  float Dp = D_p[d];
  size_t r = (size_t)b*LL + (size_t)ck*TC;
  for (int t = 0; t < TC; ++t, ++r){
    float dtv = dt[r*512 + d];
    float xv  = xc[r*512 + d];
    float dx  = dtv * xv;
    const floatx4* bp = (const floatx4*)&BC[r*32];
    float Bf[16], Cf[16];
    *(floatx4*)&Bf[0]  = bp[0];
    *(floatx4*)&Bf[4]  = bp[1];
    *(floatx4*)&Bf[8]  = bp[2];
    *(floatx4*)&Bf[12] = bp[3];
    *(floatx4*)&Cf[0]  = bp[4];
    *(floatx4*)&Cf[4]  = bp[5];
    *(floatx4*)&Cf[8]  = bp[6];
    *(floatx4*)&Cf[12] = bp[7];
    float y = 0.f;
    #pragma unroll
    for (int s = 0; s < 16; ++s){
      float a = __expf(dtv * A[s]);
      h[s] = h[s]*a + dx*Bf[s];
      y += h[s]*Cf[s];
    }
    float z  = b2f(xzb[r*1024 + 512 + d]);
    float sz = z / (1.f + __expf(-z));
    yfb[r*512 + d] = f2b((y + Dp*xv) * sz);
  }
}

// ---------------- column stats (sum, sumsq) ----------------
__global__ void colstats(const float* __restrict__ X, float* __restrict__ sums, float* __restrict__ sqs){
  int c0 = threadIdx.x;
  int row0 = blockIdx.x * 128;
  float s0=0,q0=0,s1=0,q1=0;
  for (int i = 0; i < 128; ++i){
    const float* rp = X + (size_t)(row0+i)*512;
    float a = rp[c0], b = rp[c0+256];
    s0 += a; q0 += a*a; s1 += b; q1 += b*b;
  }
  atomicAdd(&sums[c0], s0);      atomicAdd(&sqs[c0], q0);
  atomicAdd(&sums[c0+256], s1);  atomicAdd(&sqs[c0+256], q1);
}

// out0 = BN(gat)*g1+be1 + BN(h2)*g2+be2  (f32 + bf16)
__global__ void combine_out0(const float* __restrict__ gat, const float* __restrict__ h2,
                             const float* __restrict__ s1, const float* __restrict__ q1,
                             const float* __restrict__ s2, const float* __restrict__ q2,
                             const float* __restrict__ g1, const float* __restrict__ be1,
                             const float* __restrict__ g2, const float* __restrict__ be2,
                             float* __restrict__ out0, unsigned short* __restrict__ out0b){
  int t = threadIdx.x;
  int row0 = blockIdx.x * 128;
  const float invN = 1.f/16384.f;
  float sc1[2], sc2[2], off[2];
  #pragma unroll
  for (int h = 0; h < 2; ++h){
    int c = t + h*256;
    float m1 = s1[c]*invN, v1 = q1[c]*invN - m1*m1;
    float m2 = s2[c]*invN, v2 = q2[c]*invN - m2*m2;
    float a1 = rsqrtf(v1 + 1e-5f) * g1[c];
    float a2 = rsqrtf(v2 + 1e-5f) * g2[c];
    sc1[h] = a1; sc2[h] = a2;
    off[h] = be1[c] + be2[c] - m1*a1 - m2*a2;
  }
  for (int i = 0; i < 128; ++i){
    size_t ro = (size_t)(row0+i)*512;
    #pragma unroll
    for (int h = 0; h < 2; ++h){
      int c = t + h*256;
      float v = gat[ro+c]*sc1[h] + h2[ro+c]*sc2[h] + off[h];
      out0[ro+c] = v;
      out0b[ro+c] = f2b(v);
    }
  }
}

// out2 = relu(BN(out1)*g3+be3); per-batch column sums -> poolsum
__global__ void out2_pool(const float* __restrict__ out1,
                          const float* __restrict__ s3, const float* __restrict__ q3,
                          const float* __restrict__ g3, const float* __restrict__ be3,
                          float* __restrict__ poolsum){
  int t = threadIdx.x;
  int row0 = blockIdx.x * 128;
  int bidx = row0 / LL;
  const float invN = 1.f/16384.f;
  float sc[2], off[2], acc[2] = {0.f, 0.f};
  #pragma unroll
  for (int h = 0; h < 2; ++h){
    int c = t + h*256;
    float m = s3[c]*invN, v = q3[c]*invN - m*m;
    float a = rsqrtf(v + 1e-5f) * g3[c];
    sc[h] = a; off[h] = be3[c] - m*a;
  }
  for (int i = 0; i < 128; ++i){
    size_t ro = (size_t)(row0+i)*512;
    #pragma unroll
    for (int h = 0; h < 2; ++h){
      int c = t + h*256;
      float v = fmaxf(out1[ro+c]*sc[h] + off[h], 0.f);
      acc[h] += v;
    }
  }
  atomicAdd(&poolsum[bidx*512 + t], acc[0]);
  atomicAdd(&poolsum[bidx*512 + t + 256], acc[1]);
}

// final head MLP: one block per batch row
__global__ __launch_bounds__(256)
void head(const float* __restrict__ poolsum,
          const float* __restrict__ Wf1, const float* __restrict__ bf1,
          const float* __restrict__ Wf2, const float* __restrict__ bf2,
          const float* __restrict__ Wf3, const float* __restrict__ bf3,
          float* __restrict__ dout){
  int r = blockIdx.x, t = threadIdx.x;
  __shared__ float pool[512];
  __shared__ float h1s[256];
  __shared__ float h2s[128];
  for (int i = t; i < 512; i += 256){
    float v = poolsum[r*512 + i] * (1.f/2048.f);
    pool[i] = v;
    dout[8 + r*512 + i] = v;
  }
  __syncthreads();
  {
    float a = bf1[t];
    for (int k = 0; k < 512; ++k) a += pool[k] * Wf1[(size_t)k*256 + t];
    h1s[t] = fmaxf(a, 0.f);
  }
  __syncthreads();
  if (t < 128){
    float a = bf2[t];
    for (int k = 0; k < 256; ++k) a += h1s[k] * Wf2[(size_t)k*128 + t];
    h2s[t] = fmaxf(a, 0.f);
  }
  __syncthreads();
  if (t == 0){
    float a = bf3[0];
    for (int k = 0; k < 128; ++k) a += h2s[k] * Wf3[k];
    dout[r] = a;
  }
}

// ---------------- host ----------------
extern "C" void kernel_launch(void* const* d_in, const int* in_sizes, int n_in,
                              void* d_out, int out_size, void* d_ws, size_t ws_size,
                              hipStream_t stream){
  const float* x      = (const float*)d_in[0];
  const int*   ei     = (const int*)d_in[1];
  const float* W_uni  = (const float*)d_in[5];
  const float* b_uni  = (const float*)d_in[6];
  const float* W_gat  = (const float*)d_in[10];
  const float* att_s  = (const float*)d_in[11];
  const float* att_d  = (const float*)d_in[12];
  const float* b_gat  = (const float*)d_in[13];
  const float* g1     = (const float*)d_in[14];
  const float* be1    = (const float*)d_in[15];
  const float* g2     = (const float*)d_in[16];
  const float* be2    = (const float*)d_in[17];
  const float* g3     = (const float*)d_in[18];
  const float* be3    = (const float*)d_in[19];
  const float* W_in   = (const float*)d_in[20];
  const float* w_conv = (const float*)d_in[21];
  const float* b_conv = (const float*)d_in[22];
  const float* W_xp   = (const float*)d_in[23];
  const float* W_dt   = (const float*)d_in[24];
  const float* b_dt   = (const float*)d_in[25];
  const float* A_log  = (const float*)d_in[26];
  const float* D_p    = (const float*)d_in[27];
  const float* W_out  = (const float*)d_in[28];
  const float* W_m1   = (const float*)d_in[29];
  const float* b_m1   = (const float*)d_in[30];
  const float* W_m2   = (const float*)d_in[31];
  const float* b_m2   = (const float*)d_in[32];
  const float* Wf1    = (const float*)d_in[33];
  const float* bf1    = (const float*)d_in[34];
  const float* Wf2    = (const float*)d_in[35];
  const float* bf2    = (const float*)d_in[36];
  const float* Wf3    = (const float*)d_in[37];
  const float* bf3    = (const float*)d_in[38];
  float* dout = (float*)d_out;

  char* base = (char*)d_ws;
  size_t off = 0;
  auto alloc = [&](size_t b){ size_t r = off; off += (b + 255) & ~(size_t)255; return r; };

  size_t oR1    = alloc((size_t)NN*1024*2);   // Xb -> xzb -> out1 (33.5MB each, aliased)
  size_t oH0b   = alloc((size_t)NN*512*2);    // h0b bf16
  size_t oWuniT = alloc(512*1024*2);
  size_t oWgatT = alloc(512*512*2);
  size_t oWinT  = alloc(1024*512*2);
  size_t oWfusT = alloc(512*512*2);
  size_t oWbcT  = alloc(128*512*2);
  size_t oWoutT = alloc(512*512*2);
  size_t oWm1T  = alloc(1024*512*2);
  size_t oWm2T  = alloc(512*1024*2);
  size_t oBuni  = alloc(512*4);
  size_t oXh    = alloc((size_t)NN*512*2);    // xh bf16 -> yfb bf16
  size_t oAs    = alloc(NN*4);
  size_t oAd    = alloc(NN*4);
  size_t oCnt   = alloc(NN*4);
  size_t oCur   = alloc(NN*4);
  size_t oOff   = alloc((NN+1)*4);
  size_t oSrcs  = alloc((size_t)EE*4);
  size_t oAlph  = alloc((size_t)EE*4);
  size_t oGat   = alloc((size_t)NN*512*4);    // gat f32 -> mlp1b bf16
  size_t oXc    = alloc((size_t)NN*512*4);    // xc f32 -> out0 f32
  size_t oXcb   = alloc((size_t)NN*512*2);    // xcb bf16 -> Pc/Hc f32 (scan) -> out0b bf16
  size_t oDt    = alloc((size_t)NN*512*4);    // dt f32 -> h2raw f32
  size_t oBC    = alloc((size_t)NN*32*4);
  size_t oStats = alloc(6*512*4);             // s1,q1,s2,q2,s3,q3
  size_t oPool  = alloc(8*512*4);

  short* Xb   = (short*)(base + oR1);
  unsigned short* xzb = (unsigned short*)(base + oR1);
  float* out1 = (float*)(base + oR1);
  unsigned short* h0b = (unsigned short*)(base + oH0b);
  short* WuniT = (short*)(base + oWuniT);
  short* WgatT = (short*)(base + oWgatT);
  short* WinT  = (short*)(base + oWinT);
  short* WfusT = (short*)(base + oWfusT);
  short* WbcT  = (short*)(base + oWbcT);
  short* WoutT = (short*)(base + oWoutT);
  short* Wm1T  = (short*)(base + oWm1T);
  short* Wm2T  = (short*)(base + oWm2T);
  float* buniP = (float*)(base + oBuni);
  unsigned short* xh  = (unsigned short*)(base + oXh);
  unsigned short* yfb = (unsigned short*)(base + oXh);
  float* a_s = (float*)(base + oAs);
  float* a_d = (float*)(base + oAd);
  int* cnt = (int*)(base + oCnt);
  int* cur = (int*)(base + oCur);
  int* offs = (int*)(base + oOff);
  int* srcs = (int*)(base + oSrcs);
  float* alphas = (float*)(base + oAlph);
  float* gat = (float*)(base + oGat);
  unsigned short* mlp1b = (unsigned short*)(base + oGat);
  float* xc = (float*)(base + oXc);
  float* out0 = (float*)(base + oXc);
  unsigned short* xcb  = (unsigned short*)(base + oXcb);
  unsigned short* out0b = (unsigned short*)(base + oXcb);
  // scan scratch aliases the xcb region (dead between BC-GEMM and combine_out0):
  // Pc = 8*32*512*16 f32 = 8 MB, Hc same; total 16 MB <= 16.78 MB region.
  float* Pc = (float*)(base + oXcb);
  float* Hc = Pc + (size_t)8*NCK*512*16;
  float* dt = (float*)(base + oDt);
  float* h2raw = (float*)(base + oDt);
  float* BC = (float*)(base + oBC);
  float* s1 = (float*)(base + oStats);
  float* q1 = s1 + 512;
  float* s2 = q1 + 512;
  float* q2 = s2 + 512;
  float* s3 = q2 + 512;
  float* q3 = s3 + 512;
  float* poolsum = (float*)(base + oPool);

  // zero the accumulators
  hipMemsetAsync(cnt, 0, NN*4, stream);
  hipMemsetAsync(s1, 0, 6*512*4, stream);
  hipMemsetAsync(poolsum, 0, 8*512*4, stream);

  // prep: convert/transpose weights, convert x, fuse W_xp@W_dt
  transposeW<<<(512*1024+255)/256, 256, 0, stream>>>(W_uni, WuniT, 1024, 496, 512, 496, 0);
  transposeW<<<(512*512+255)/256, 256, 0, stream>>>(W_gat, WgatT, 512, 512, 512, 512, 0);
  transposeW<<<(1024*512+255)/256, 256, 0, stream>>>(W_in, WinT, 512, 1024, 1024, 1024, 0);
  transposeW<<<(128*512+255)/256, 256, 0, stream>>>(W_xp, WbcT, 512, 32, 128, 64, 32);
  transposeW<<<(512*512+255)/256, 256, 0, stream>>>(W_out, WoutT, 512, 512, 512, 512, 0);
  transposeW<<<(1024*512+255)/256, 256, 0, stream>>>(W_m1, Wm1T, 512, 1024, 1024, 1024, 0);
  transposeW<<<(512*1024+255)/256, 256, 0, stream>>>(W_m2, Wm2T, 1024, 512, 512, 512, 0);
  fuse_wdt<<<(512*512+255)/256, 256, 0, stream>>>(W_xp, W_dt, WfusT);
  pad_bias<<<2, 256, 0, stream>>>(b_uni, buniP);
  conv_x<<<(NN*1024+255)/256, 256, 0, stream>>>(x, Xb);

  dim3 g4(128, 4), g8(128, 8), g1b(128, 1);
  // h0 = [x@W_uni + b_uni | pe]
  gemm_bt<<<g4, 256, 0, stream>>>(Xb, WuniT, nullptr, h0b, buniP, nullptr, 1024, 512, 0);
  pe_fill<<<(NN+255)/256, 256, 0, stream>>>(x, h0b);
  // xh = h0 @ W_gat  (bf16)
  gemm_bt<<<g4, 256, 0, stream>>>((const short*)h0b, WgatT, nullptr, xh, nullptr, nullptr, 512, 512, 0);
  att_proj<<<NN/4, 256, 0, stream>>>(xh, att_s, att_d, a_s, a_d);
  // GAT
  gat_hist<<<EE/256, 256, 0, stream>>>(ei, cnt);
  gat_prefix<<<1, 256, 0, stream>>>(cnt, offs, cur);
  gat_scatter<<<EE/256, 256, 0, stream>>>(ei, a_s, a_d, cur, srcs, alphas);
  gat_agg<<<NN/4, 256, 0, stream>>>(offs, srcs, alphas, xh, a_s, a_d, b_gat, gat);
  colstats<<<128, 256, 0, stream>>>(gat, s1, q1);
  // Mamba path
  gemm_bt<<<g8, 256, 0, stream>>>((const short*)h0b, WinT, nullptr, xzb, nullptr, nullptr, 512, 1024, 0);
  {
    dim3 gc(NN, 2);
    conv_silu<<<gc, 256, 0, stream>>>(xzb, w_conv, b_conv, xc, xcb);
  }
  gemm_bt<<<g4, 256, 0, stream>>>((const short*)xcb, WfusT, dt, nullptr, b_dt, nullptr, 512, 512, 2);
  gemm_bt<<<g1b, 256, 0, stream>>>((const short*)xcb, WbcT, BC, nullptr, nullptr, nullptr, 512, 32, 0);
  // chunked parallel scan (xcb region is dead from here until combine_out0)
  {
    dim3 gs(8*NCK, 2);
    ssm_scan1<<<gs, 256, 0, stream>>>(dt, xc, BC, A_log, Pc, Hc);
    ssm_carry<<<256, 256, 0, stream>>>(Pc, Hc);
    ssm_scan2<<<gs, 256, 0, stream>>>(dt, xc, BC, xzb, A_log, D_p, Hc, yfb);
  }
  gemm_bt<<<g4, 256, 0, stream>>>((const short*)yfb, WoutT, h2raw, nullptr, nullptr, nullptr, 512, 512, 0);
  colstats<<<128, 256, 0, stream>>>(h2raw, s2, q2);
  // combine + MLP residual
  combine_out0<<<128, 256, 0, stream>>>(gat, h2raw, s1, q1, s2, q2, g1, be1, g2, be2, out0, out0b);
  gemm_bt<<<g8, 256, 0, stream>>>((const short*)out0b, Wm1T, nullptr, mlp1b, b_m1, nullptr, 512, 1024, 1);
  gemm_bt<<<g4, 256, 0, stream>>>((const short*)mlp1b, Wm2T, out1, nullptr, b_m2, out0, 1024, 512, 0);
  colstats<<<128, 256, 0, stream>>>(out1, s3, q3);
  out2_pool<<<128, 256, 0, stream>>>(out1, s3, q3, g3, be3, poolsum);
  head<<<8, 256, 0, stream>>>(poolsum, Wf1, bf1, Wf2, bf2, Wf3, bf3, dout);
}